// Round 11
// baseline (142.141 us; speedup 1.0000x reference)
//
#include <hip/hip_runtime.h>
#include <hip/hip_bf16.h>

#define B_ 8
#define C_ 512
#define N_ 1024
#define HEADS_ 4
#define DK_ 128
#define R_ 128

typedef float f32x4 __attribute__((ext_vector_type(4)));
typedef __bf16 bf16x8 __attribute__((ext_vector_type(8)));
typedef short short4v __attribute__((ext_vector_type(4)));
typedef unsigned short u16;

constexpr float kScale = 0.08838834764831845f; // 1/sqrt(128)

// ---- workspace layout (bytes); ws_size = 256 MiB ----
#define OFF_P   0u
#define OFF_SS  16384u
#define OFF_WB  32768u
#define OFF_XT  1605632u
#define OFF_QT  9994240u
#define OFF_KT  18382848u
#define OFF_V   26771456u
#define OFF_DEN 35160064u                // den [B*H][N] f32 (atomic) 128KB
#define OFF_G   35291136u                // gate dot [B][N] f32    32KB
#define OFF_O1  35323904u                // o half-1 [B][C][N] f32 16MB

__device__ __forceinline__ u16 f2b(float f) {
  __hip_bfloat16 h = __float2bfloat16(f);
  return __builtin_bit_cast(u16, h);
}

typedef const __attribute__((address_space(1))) unsigned int* gptr_t;
typedef __attribute__((address_space(3))) unsigned int* lptr_t;
__device__ __forceinline__ void gload16(const void* g, void* l) {
  __builtin_amdgcn_global_load_lds((gptr_t)g, (lptr_t)l, 16, 0, 0);
}

__device__ __forceinline__ f32x4 mfma16(bf16x8 a, bf16x8 b, f32x4 c) {
  return __builtin_amdgcn_mfma_f32_16x16x32_bf16(a, b, c, 0, 0, 0);
}

#if __has_builtin(__builtin_amdgcn_mfma_f32_16x16x16bf16_1k)
__device__ __forceinline__ f32x4 mfma_k16(short4v a, short4v b, f32x4 c) {
  return __builtin_amdgcn_mfma_f32_16x16x16bf16_1k(a, b, c, 0, 0, 0);
}
#else
__device__ __forceinline__ f32x4 mfma_k16(short4v a, short4v b, f32x4 c) {
  bf16x8 a8 = {}, b8 = {};
  for (int e = 0; e < 4; e++) {
    ((u16*)&a8)[e] = ((u16*)&a)[e];
    ((u16*)&b8)[e] = ((u16*)&b)[e];
  }
  return __builtin_amdgcn_mfma_f32_16x16x32_bf16(a8, b8, c, 0, 0, 0);
}
#endif

// ---------------- pool ----------------
__global__ __launch_bounds__(64) void k_pool(const float* __restrict__ x,
                                             float* __restrict__ p) {
  int bc = blockIdx.x, lane = threadIdx.x;
  const float4* row = (const float4*)(x + (size_t)bc * N_);
  float s = 0.f;
  for (int i = lane; i < N_ / 4; i += 64) {
    float4 t = row[i];
    s += t.x + t.y + t.z + t.w;
  }
  for (int o = 32; o > 0; o >>= 1) s += __shfl_down(s, o, 64);
  if (lane == 0) p[bc] = s * (1.0f / N_);
}

// ---------------- SE MLP ----------------
__global__ __launch_bounds__(256) void k_se(const float* __restrict__ p,
                                            const float* __restrict__ fc1w,
                                            const float* __restrict__ fc1b,
                                            const float* __restrict__ fc2w,
                                            const float* __restrict__ fc2b,
                                            float* __restrict__ ss) {
  __shared__ float pl[C_];
  __shared__ float f1[R_];
  int b = blockIdx.x, t = threadIdx.x;
  for (int c = t; c < C_; c += 256) pl[c] = p[b * C_ + c];
  __syncthreads();
  if (t < R_) {
    float a = fc1b[t];
    for (int c = 0; c < C_; c++) a += pl[c] * fc1w[t * C_ + c];
    f1[t] = fmaxf(a, 0.f);
  }
  __syncthreads();
  for (int c = t; c < C_; c += 256) {
    float a = fc2b[c];
    for (int j = 0; j < R_; j++) a += f1[j] * fc2w[c * R_ + j];
    ss[b * C_ + c] = 1.f + 1.f / (1.f + __expf(-a));
  }
}

// ---------------- cast weights + zero g + zero den ----------------
__global__ __launch_bounds__(256) void k_castw_zero(const float* __restrict__ wq,
                                                    const float* __restrict__ wk,
                                                    const float* __restrict__ wv,
                                                    u16* __restrict__ wb,
                                                    float* __restrict__ g,
                                                    float* __restrict__ den) {
  int bid = blockIdx.x;
  if (bid >= 800) {
    den[(bid - 800) * 256 + threadIdx.x] = 0.f;
    return;
  }
  if (bid >= 768) {
    g[(bid - 768) * 256 + threadIdx.x] = 0.f;
    return;
  }
  int i = bid * 256 + threadIdx.x;
  int idx = i * 4;
  const float* srcs[3] = {wq, wk, wv};
  int w = idx / (C_ * C_), off = idx % (C_ * C_);
  float4 v = *(const float4*)(srcs[w] + off);
  u16* d = wb + idx;
  d[0] = f2b(v.x); d[1] = f2b(v.y); d[2] = f2b(v.z); d[3] = f2b(v.w);
}

// ---------------- x1^T ----------------
__global__ __launch_bounds__(256) void k_xt(const float* __restrict__ x,
                                            const float* __restrict__ ss,
                                            u16* __restrict__ xt) {
  int b = blockIdx.z, c0 = blockIdx.y * 64, n0 = blockIdx.x * 64;
  __shared__ float tile[64][65];
  int t = threadIdx.x;
  int cr = t >> 4, nc4 = (t & 15) * 4;
  for (int j = 0; j < 4; j++) {
    int c = cr + j * 16;
    float sc = ss[b * C_ + c0 + c];
    float4 v = *(const float4*)(x + ((size_t)b * C_ + c0 + c) * N_ + n0 + nc4);
    tile[c][nc4 + 0] = v.x * sc;
    tile[c][nc4 + 1] = v.y * sc;
    tile[c][nc4 + 2] = v.z * sc;
    tile[c][nc4 + 3] = v.w * sc;
  }
  __syncthreads();
  int nr = t >> 2, cc = (t & 3) * 16;
  u16 ov[16];
  for (int m = 0; m < 16; m++) ov[m] = f2b(tile[cc + m][nr]);
  u16* dst = xt + ((size_t)b * N_ + n0 + nr) * C_ + c0 + cc;
  for (int m = 0; m < 16; m++) dst[m] = ov[m];
}

// ---------------- QKV GEMM ----------------
__global__ __launch_bounds__(256) void k_qkv(const u16* __restrict__ xt,
                                             const u16* __restrict__ wb,
                                             const float* __restrict__ bq,
                                             const float* __restrict__ bk,
                                             const float* __restrict__ bv,
                                             u16* __restrict__ qt,
                                             u16* __restrict__ kt,
                                             u16* __restrict__ v) {
  __shared__ char smem[32768];
  int b = blockIdx.y / 3, sel = blockIdx.y % 3;
  int tile = blockIdx.x;
  const char *Ab, *Bb;
  u16* out;
  const float* bias;
  int mt, nt, rstride;
  size_t xtoff = (size_t)b * N_ * C_;
  if (sel < 2) {
    mt = tile & 7; nt = tile >> 3;
    Ab = (const char*)(xt + xtoff + (size_t)mt * 128 * C_);
    Bb = (const char*)(wb + (size_t)sel * C_ * C_ + (size_t)nt * 128 * C_);
    out = (sel ? kt : qt) + xtoff;
    bias = sel ? bk : bq;
    rstride = C_ * 2;
  } else {
    mt = tile & 3; nt = tile >> 2;
    Ab = (const char*)(wb + (size_t)2 * C_ * C_ + (size_t)mt * 128 * C_);
    Bb = (const char*)(xt + xtoff + (size_t)nt * 128 * C_);
    out = v + (size_t)b * C_ * N_;
    bias = bv;
    rstride = N_ * 2;
  }
  int t = threadIdx.x, lane = t & 63, wid = t >> 6;
  int wr = wid >> 1, wc = wid & 1;
  const f32x4 z4 = {0.f, 0.f, 0.f, 0.f};
  f32x4 acc[4][4];
  for (int i = 0; i < 4; i++)
    for (int j = 0; j < 4; j++) acc[i][j] = z4;

  char* lA = smem;
  char* lB = smem + 16384;
  for (int ko = 0; ko < C_; ko += 64) {
    __syncthreads();
    for (int i = wid; i < 16; i += 4) {
      int beta = i * 1024 + lane * 16;
      int row = beta >> 7, cb = (beta & 127) ^ ((row & 7) << 4);
      gload16(Ab + (size_t)row * 1024 + ko * 2 + cb, lA + beta);
    }
    for (int i = wid; i < 16; i += 4) {
      int beta = i * 1024 + lane * 16;
      int row = beta >> 7, cb = (beta & 127) ^ ((row & 7) << 4);
      gload16(Bb + (size_t)row * 1024 + ko * 2 + cb, lB + beta);
    }
    __syncthreads();
    for (int ks = 0; ks < 2; ks++) {
      int kb = ks * 64 + (lane >> 4) * 16;
      bf16x8 af[4], bfr[4];
      for (int fi = 0; fi < 4; fi++) {
        int row = wr * 64 + fi * 16 + (lane & 15);
        af[fi] = *(const bf16x8*)(lA + row * 128 + (kb ^ ((row & 7) << 4)));
      }
      for (int fj = 0; fj < 4; fj++) {
        int row = wc * 64 + fj * 16 + (lane & 15);
        bfr[fj] = *(const bf16x8*)(lB + row * 128 + (kb ^ ((row & 7) << 4)));
      }
      for (int fi = 0; fi < 4; fi++)
        for (int fj = 0; fj < 4; fj++)
          acc[fi][fj] = mfma16(af[fi], bfr[fj], acc[fi][fj]);
    }
  }
  __syncthreads();
  for (int fi = 0; fi < 4; fi++)
    for (int fj = 0; fj < 4; fj++) {
      int colb = wc * 64 + fj * 16 + (lane & 15);
      for (int r = 0; r < 4; r++) {
        int rowb = wr * 64 + fi * 16 + (lane >> 4) * 4 + r;
        float bva = (sel < 2) ? bias[nt * 128 + colb] : bias[mt * 128 + rowb];
        float val = acc[fi][fj][r] + bva;
        int byte = rowb * 256 + ((colb * 2) ^ ((rowb & 7) << 4));
        *(u16*)(smem + byte) = f2b(val);
      }
    }
  __syncthreads();
  for (int i = t; i < 2048; i += 256) {
    int row = i >> 4, cb = (i & 15) * 16;
    bf16x8 val = *(const bf16x8*)(smem + row * 256 + (cb ^ ((row & 7) << 4)));
    *(bf16x8*)((char*)out + (size_t)(mt * 128 + row) * rstride + nt * 256 + cb) = val;
  }
}

// ---------------- pass A: den[bh][n] += sum_{m in quarter} exp(scale*S[n,m]) ----------------
// grid (bh, 8 n-tiles of 128, 4 m-quarters) = 1024 blocks; lK dbuf 2x16KB ->
// 4 blocks/CU, 16 waves/CU. Wave owns 32 n; chunks of 64 m (4 per block).
__global__ __launch_bounds__(256) void k_passA(const u16* __restrict__ qt,
                                               const u16* __restrict__ kt,
                                               float* __restrict__ den) {
  __shared__ char lK[2][16384]; // [64 m][128 d] swizzled, x2
  int bh = blockIdx.x, nb = blockIdx.y * 128, mq = blockIdx.z;
  int b = bh >> 2, h = bh & 3;
  const char* qb = (const char*)(qt + (size_t)b * N_ * C_ + h * DK_);
  const char* kb = (const char*)(kt + (size_t)b * N_ * C_ + h * DK_);
  int t = threadIdx.x, lane = t & 63, wid = t >> 6; // wid 0..3
  bf16x8 aq[2][4];
  for (int gq = 0; gq < 2; gq++) {
    const char* qr = qb + (size_t)(nb + wid * 32 + gq * 16 + (lane & 15)) * (C_ * 2);
    for (int ks = 0; ks < 4; ks++)
      aq[gq][ks] = *(const bf16x8*)(qr + ks * 64 + (lane >> 4) * 16);
  }
  float sacc[2][4] = {{0.f, 0.f, 0.f, 0.f}, {0.f, 0.f, 0.f, 0.f}};
  const f32x4 z4 = {0.f, 0.f, 0.f, 0.f};
  int m0 = mq * 256;
  for (int i = wid; i < 16; i += 4) {
    int beta = i * 1024 + lane * 16;
    int row = beta >> 8, cb = (beta & 255) ^ ((row & 7) << 4);
    gload16(kb + (size_t)(m0 + row) * (C_ * 2) + cb, lK[0] + beta);
  }
  for (int mc = 0; mc < 4; mc++) {
    int cur = mc & 1;
    __syncthreads();
    if (mc < 3) {
      int mnext = m0 + (mc + 1) * 64;
      for (int i = wid; i < 16; i += 4) {
        int beta = i * 1024 + lane * 16;
        int row = beta >> 8, cb = (beta & 255) ^ ((row & 7) << 4);
        gload16(kb + (size_t)(mnext + row) * (C_ * 2) + cb, lK[cur ^ 1] + beta);
      }
    }
    for (int fj = 0; fj < 4; fj++) {
      f32x4 s0 = z4, s1 = z4;
      for (int ks = 0; ks < 4; ks++) {
        int row = fj * 16 + (lane & 15);
        bf16x8 bk_ = *(const bf16x8*)(lK[cur] + row * 256 +
                                      ((ks * 64 + (lane >> 4) * 16) ^ ((row & 7) << 4)));
        s0 = mfma16(aq[0][ks], bk_, s0);
        s1 = mfma16(aq[1][ks], bk_, s1);
      }
      for (int r = 0; r < 4; r++) {
        sacc[0][r] += __expf(s0[r] * kScale);
        sacc[1][r] += __expf(s1[r] * kScale);
      }
    }
  }
  for (int gq = 0; gq < 2; gq++)
    for (int r = 0; r < 4; r++) {
      float vv = sacc[gq][r];
      for (int m = 1; m < 16; m <<= 1) vv += __shfl_xor(vv, m, 64);
      sacc[gq][r] = vv;
    }
  if ((lane & 15) == 0) {
    for (int gq = 0; gq < 2; gq++) {
      int n = nb + wid * 32 + gq * 16 + (lane >> 4) * 4;
      for (int r = 0; r < 4; r++)
        atomicAdd(&den[(size_t)bh * N_ + n + r], sacc[gq][r]);
    }
  }
}

// ---------------- pass B: 32-n chunks, 33KB LDS -> 4 blocks/CU ----------------
// grid (bh, 16 m-tiles of 64, 2 n-halves) = 1024 blocks. Wave owns 16 m;
// 16 chunks of 32 n per block. Half 0 -> out, half 1 -> o1.
__global__ __launch_bounds__(256) void k_passB(const u16* __restrict__ qt,
                                               const u16* __restrict__ kt,
                                               const u16* __restrict__ v,
                                               const float* __restrict__ den,
                                               const float* __restrict__ gw,
                                               float* __restrict__ out0,
                                               float* __restrict__ o1,
                                               float* __restrict__ g) {
  __shared__ char lQ[2][8192]; // [32 n][128 d] swz (256B rows), x2
  __shared__ char lV[2][8192]; // [128 d][32 n] swz (64B rows, 4-slot), x2
  __shared__ float gacc[64];
  int bh = blockIdx.x, mb = blockIdx.y * 64, nh = blockIdx.z;
  int b = bh >> 2, h = bh & 3;
  const char* qb = (const char*)(qt + (size_t)b * N_ * C_ + h * DK_);
  const char* kb = (const char*)(kt + (size_t)b * N_ * C_ + h * DK_);
  const char* vb = (const char*)(v + ((size_t)b * C_ + h * DK_) * N_);
  float* ob = (nh ? o1 : out0) + ((size_t)b * C_ + h * DK_) * N_ + mb;
  const float* denb = den + (size_t)bh * N_;
  int t = threadIdx.x, lane = t & 63, wid = t >> 6; // wid 0..3
  bf16x8 bkm[4]; // wave's 16 m-rows of K
  {
    const char* kr = kb + (size_t)(mb + wid * 16 + (lane & 15)) * (C_ * 2);
    for (int ks = 0; ks < 4; ks++)
      bkm[ks] = *(const bf16x8*)(kr + ks * 64 + (lane >> 4) * 16);
  }
  if (t < 64) gacc[t] = 0.f;
  const f32x4 z4 = {0.f, 0.f, 0.f, 0.f};
  f32x4 oacc[8];
  for (int j = 0; j < 8; j++) oacc[j] = z4;

  int nbase = nh * 512;
  // prologue: stage chunk 0
  for (int i = wid; i < 8; i += 4) {
    int beta = i * 1024 + lane * 16;
    int row = beta >> 8, cb = (beta & 255) ^ ((row & 7) << 4);
    gload16(qb + (size_t)(nbase + row) * (C_ * 2) + cb, lQ[0] + beta);
  }
  for (int i = wid; i < 8; i += 4) {
    int beta = i * 1024 + lane * 16;
    int row = beta >> 6, cb = (beta & 63) ^ ((row & 3) << 4);
    gload16(vb + (size_t)row * (N_ * 2) + nbase * 2 + cb, lV[0] + beta);
  }

  for (int c = 0; c < 16; c++) {
    int n0 = nbase + c * 32, cur = c & 1;
    __syncthreads();
    if (c < 15) {
      int nn = n0 + 32;
      for (int i = wid; i < 8; i += 4) {
        int beta = i * 1024 + lane * 16;
        int row = beta >> 8, cb = (beta & 255) ^ ((row & 7) << 4);
        gload16(qb + (size_t)(nn + row) * (C_ * 2) + cb, lQ[cur ^ 1] + beta);
      }
      for (int i = wid; i < 8; i += 4) {
        int beta = i * 1024 + lane * 16;
        int row = beta >> 6, cb = (beta & 63) ^ ((row & 3) << 4);
        gload16(vb + (size_t)row * (N_ * 2) + nn * 2 + cb, lV[cur ^ 1] + beta);
      }
    }
    // S^T phase -> register P fragments (2 x 16-n slices)
    short4v pf[2];
    for (int fj = 0; fj < 2; fj++) {
      f32x4 s = z4;
      int qrow = fj * 16 + (lane & 15);
      const char* qr = lQ[cur] + qrow * 256;
      int qsw = (qrow & 7) << 4;
      for (int ks = 0; ks < 4; ks++) {
        bf16x8 aq = *(const bf16x8*)(qr + ((ks * 64 + (lane >> 4) * 16) ^ qsw));
        s = mfma16(aq, bkm[ks], s); // A=q(n), B=k(m) -> D[n][m]
      }
      float4 d4 = *(const float4*)(denb + n0 + fj * 16 + (lane >> 4) * 4);
      short4v pp;
      pp[0] = (short)f2b(__expf(s[0] * kScale) / d4.x);
      pp[1] = (short)f2b(__expf(s[1] * kScale) / d4.y);
      pp[2] = (short)f2b(__expf(s[2] * kScale) / d4.z);
      pp[3] = (short)f2b(__expf(s[3] * kScale) / d4.w);
      pf[fj] = pp;
    }
    // PV phase: A=v fragments (b64 LDS reads), B=pf registers
    for (int fd = 0; fd < 8; fd++) {
      int row = fd * 16 + (lane & 15);
      const char* vr = lV[cur] + row * 64;
      int sw = (row & 3) << 4;
      for (int fj = 0; fj < 2; fj++) {
        short4v av = *(const short4v*)(vr + ((fj * 32 + (lane >> 4) * 8) ^ sw));
        oacc[fd] = mfma_k16(av, pf[fj], oacc[fd]);
      }
    }
  }
  // epilogue: store o-half + fused gate partial
  __syncthreads();
  float part = 0.f;
  int mcol = wid * 16 + (lane & 15);
  for (int fd = 0; fd < 8; fd++) {
    float4 gwv = *(const float4*)(gw + h * DK_ + fd * 16 + (lane >> 4) * 4);
    float gwa[4] = {gwv.x, gwv.y, gwv.z, gwv.w};
    for (int r = 0; r < 4; r++) {
      float val = oacc[fd][r];
      int d = fd * 16 + (lane >> 4) * 4 + r;
      ob[(size_t)d * N_ + mcol] = val;
      part += gwa[r] * val;
    }
  }
  atomicAdd(&gacc[mcol], part);
  __syncthreads();
  if (t < 64) atomicAdd(&g[(size_t)b * N_ + mb + t], gacc[t]);
}

// ---------------- gate apply: out = (out + o1) * (1 + sigmoid(g + gb)) ----------------
__global__ __launch_bounds__(256) void k_gate_apply(const float* __restrict__ g,
                                                    const float* __restrict__ gb,
                                                    const float* __restrict__ o1,
                                                    float* __restrict__ out) {
  size_t i = ((size_t)blockIdx.x * 256 + threadIdx.x) * 4;
  int b = (int)(i / ((size_t)C_ * N_));
  int n = (int)(i & (N_ - 1));
  float4 gv = *(const float4*)(g + (size_t)b * N_ + n);
  float bias = gb[0];
  float4 v0 = *(float4*)(out + i);
  float4 v1 = *(const float4*)(o1 + i);
  float ox = v0.x + v1.x, oy = v0.y + v1.y, oz = v0.z + v1.z, ow = v0.w + v1.w;
  ox *= 1.f + 1.f / (1.f + __expf(-(gv.x + bias)));
  oy *= 1.f + 1.f / (1.f + __expf(-(gv.y + bias)));
  oz *= 1.f + 1.f / (1.f + __expf(-(gv.z + bias)));
  ow *= 1.f + 1.f / (1.f + __expf(-(gv.w + bias)));
  float4 r = {ox, oy, oz, ow};
  *(float4*)(out + i) = r;
}

extern "C" void kernel_launch(void* const* d_in, const int* in_sizes, int n_in,
                              void* d_out, int out_size, void* d_ws, size_t ws_size,
                              hipStream_t stream) {
  const float* x    = (const float*)d_in[0];
  const float* wq   = (const float*)d_in[1];
  const float* bq   = (const float*)d_in[2];
  const float* wk   = (const float*)d_in[3];
  const float* bk   = (const float*)d_in[4];
  const float* wv   = (const float*)d_in[5];
  const float* bv   = (const float*)d_in[6];
  const float* fc1w = (const float*)d_in[7];
  const float* fc1b = (const float*)d_in[8];
  const float* fc2w = (const float*)d_in[9];
  const float* fc2b = (const float*)d_in[10];
  const float* gw   = (const float*)d_in[11];
  const float* gb   = (const float*)d_in[12];
  float* out = (float*)d_out;
  char* ws = (char*)d_ws;

  float* p   = (float*)(ws + OFF_P);
  float* ssc = (float*)(ws + OFF_SS);
  u16* wb  = (u16*)(ws + OFF_WB);
  u16* xt  = (u16*)(ws + OFF_XT);
  u16* qt  = (u16*)(ws + OFF_QT);
  u16* kt  = (u16*)(ws + OFF_KT);
  u16* v   = (u16*)(ws + OFF_V);
  float* den = (float*)(ws + OFF_DEN);
  float* g   = (float*)(ws + OFF_G);
  float* o1  = (float*)(ws + OFF_O1);

  k_pool<<<B_ * C_, 64, 0, stream>>>(x, p);
  k_castw_zero<<<928, 256, 0, stream>>>(wq, wk, wv, wb, g, den);
  k_se<<<B_, 256, 0, stream>>>(p, fc1w, fc1b, fc2w, fc2b, ssc);
  k_xt<<<dim3(16, 8, B_), 256, 0, stream>>>(x, ssc, xt);
  k_qkv<<<dim3(32, B_ * 3), 256, 0, stream>>>(xt, wb, bq, bk, bv, qt, kt, v);
  k_passA<<<dim3(32, 8, 4), 256, 0, stream>>>(qt, kt, den);
  k_passB<<<dim3(32, 16, 2), 256, 0, stream>>>(qt, kt, v, den, gw, out, o1, g);
  k_gate_apply<<<B_ * C_ * N_ / 1024, 256, 0, stream>>>(g, gb, o1, out);
}

// Round 12
// 120.529 us; speedup vs baseline: 1.1793x; 1.1793x over previous
//
#include <hip/hip_runtime.h>
#include <hip/hip_bf16.h>

#define B_ 8
#define C_ 512
#define N_ 1024
#define HEADS_ 4
#define DK_ 128
#define R_ 128

typedef float f32x4 __attribute__((ext_vector_type(4)));
typedef __bf16 bf16x8 __attribute__((ext_vector_type(8)));
typedef short short4v __attribute__((ext_vector_type(4)));
typedef unsigned short u16;

constexpr float kScale = 0.08838834764831845f; // 1/sqrt(128)

// ---- workspace layout (bytes) ----
#define OFF_P   0u
#define OFF_SS  16384u
#define OFF_WB  32768u
#define OFF_XT  1605632u
#define OFF_QT  9994240u
#define OFF_KT  18382848u
#define OFF_V   26771456u
#define OFF_DEN 35160064u                // invden [B*H][N] f32    128KB
#define OFF_G   35291136u                // gate dot [B][N] f32    32KB

__device__ __forceinline__ u16 f2b(float f) {
  __hip_bfloat16 h = __float2bfloat16(f);
  return __builtin_bit_cast(u16, h);
}

typedef const __attribute__((address_space(1))) unsigned int* gptr_t;
typedef __attribute__((address_space(3))) unsigned int* lptr_t;
__device__ __forceinline__ void gload16(const void* g, void* l) {
  __builtin_amdgcn_global_load_lds((gptr_t)g, (lptr_t)l, 16, 0, 0);
}

__device__ __forceinline__ f32x4 mfma16(bf16x8 a, bf16x8 b, f32x4 c) {
  return __builtin_amdgcn_mfma_f32_16x16x32_bf16(a, b, c, 0, 0, 0);
}

#if __has_builtin(__builtin_amdgcn_mfma_f32_16x16x16bf16_1k)
__device__ __forceinline__ f32x4 mfma_k16(short4v a, short4v b, f32x4 c) {
  return __builtin_amdgcn_mfma_f32_16x16x16bf16_1k(a, b, c, 0, 0, 0);
}
#else
__device__ __forceinline__ f32x4 mfma_k16(short4v a, short4v b, f32x4 c) {
  bf16x8 a8 = {}, b8 = {};
  for (int e = 0; e < 4; e++) {
    ((u16*)&a8)[e] = ((u16*)&a)[e];
    ((u16*)&b8)[e] = ((u16*)&b)[e];
  }
  return __builtin_amdgcn_mfma_f32_16x16x32_bf16(a8, b8, c, 0, 0, 0);
}
#endif

// ---------------- pool ----------------
__global__ __launch_bounds__(64) void k_pool(const float* __restrict__ x,
                                             float* __restrict__ p) {
  int bc = blockIdx.x, lane = threadIdx.x;
  const float4* row = (const float4*)(x + (size_t)bc * N_);
  float s = 0.f;
  for (int i = lane; i < N_ / 4; i += 64) {
    float4 t = row[i];
    s += t.x + t.y + t.z + t.w;
  }
  for (int o = 32; o > 0; o >>= 1) s += __shfl_down(s, o, 64);
  if (lane == 0) p[bc] = s * (1.0f / N_);
}

// ---------------- SE MLP ----------------
__global__ __launch_bounds__(256) void k_se(const float* __restrict__ p,
                                            const float* __restrict__ fc1w,
                                            const float* __restrict__ fc1b,
                                            const float* __restrict__ fc2w,
                                            const float* __restrict__ fc2b,
                                            float* __restrict__ ss) {
  __shared__ float pl[C_];
  __shared__ float f1[R_];
  int b = blockIdx.x, t = threadIdx.x;
  for (int c = t; c < C_; c += 256) pl[c] = p[b * C_ + c];
  __syncthreads();
  if (t < R_) {
    float a = fc1b[t];
    for (int c = 0; c < C_; c++) a += pl[c] * fc1w[t * C_ + c];
    f1[t] = fmaxf(a, 0.f);
  }
  __syncthreads();
  for (int c = t; c < C_; c += 256) {
    float a = fc2b[c];
    for (int j = 0; j < R_; j++) a += f1[j] * fc2w[c * R_ + j];
    ss[b * C_ + c] = 1.f + 1.f / (1.f + __expf(-a));
  }
}

// ---------------- cast weights + zero g ----------------
__global__ __launch_bounds__(256) void k_castw_zero(const float* __restrict__ wq,
                                                    const float* __restrict__ wk,
                                                    const float* __restrict__ wv,
                                                    u16* __restrict__ wb,
                                                    float* __restrict__ g) {
  int bid = blockIdx.x;
  if (bid >= 768) {
    g[(bid - 768) * 256 + threadIdx.x] = 0.f;
    return;
  }
  int i = bid * 256 + threadIdx.x;
  int idx = i * 4;
  const float* srcs[3] = {wq, wk, wv};
  int w = idx / (C_ * C_), off = idx % (C_ * C_);
  float4 v = *(const float4*)(srcs[w] + off);
  u16* d = wb + idx;
  d[0] = f2b(v.x); d[1] = f2b(v.y); d[2] = f2b(v.z); d[3] = f2b(v.w);
}

// ---------------- x1^T ----------------
__global__ __launch_bounds__(256) void k_xt(const float* __restrict__ x,
                                            const float* __restrict__ ss,
                                            u16* __restrict__ xt) {
  int b = blockIdx.z, c0 = blockIdx.y * 64, n0 = blockIdx.x * 64;
  __shared__ float tile[64][65];
  int t = threadIdx.x;
  int cr = t >> 4, nc4 = (t & 15) * 4;
  for (int j = 0; j < 4; j++) {
    int c = cr + j * 16;
    float sc = ss[b * C_ + c0 + c];
    float4 v = *(const float4*)(x + ((size_t)b * C_ + c0 + c) * N_ + n0 + nc4);
    tile[c][nc4 + 0] = v.x * sc;
    tile[c][nc4 + 1] = v.y * sc;
    tile[c][nc4 + 2] = v.z * sc;
    tile[c][nc4 + 3] = v.w * sc;
  }
  __syncthreads();
  int nr = t >> 2, cc = (t & 3) * 16;
  u16 ov[16];
  for (int m = 0; m < 16; m++) ov[m] = f2b(tile[cc + m][nr]);
  u16* dst = xt + ((size_t)b * N_ + n0 + nr) * C_ + c0 + cc;
  for (int m = 0; m < 16; m++) dst[m] = ov[m];
}

// ---------------- QKV GEMM (bf16 MFMA, 128x128 tile, BK=64) ----------------
// lA/lB rows are 128 B (64 k x 2B): 8 slots, 3-bit swizzle (unchanged).
__global__ __launch_bounds__(256) void k_qkv(const u16* __restrict__ xt,
                                             const u16* __restrict__ wb,
                                             const float* __restrict__ bq,
                                             const float* __restrict__ bk,
                                             const float* __restrict__ bv,
                                             u16* __restrict__ qt,
                                             u16* __restrict__ kt,
                                             u16* __restrict__ v) {
  __shared__ char smem[32768];
  int b = blockIdx.y / 3, sel = blockIdx.y % 3;
  int tile = blockIdx.x;
  const char *Ab, *Bb;
  u16* out;
  const float* bias;
  int mt, nt, rstride;
  size_t xtoff = (size_t)b * N_ * C_;
  if (sel < 2) {
    mt = tile & 7; nt = tile >> 3;
    Ab = (const char*)(xt + xtoff + (size_t)mt * 128 * C_);
    Bb = (const char*)(wb + (size_t)sel * C_ * C_ + (size_t)nt * 128 * C_);
    out = (sel ? kt : qt) + xtoff;
    bias = sel ? bk : bq;
    rstride = C_ * 2;
  } else {
    mt = tile & 3; nt = tile >> 2;
    Ab = (const char*)(wb + (size_t)2 * C_ * C_ + (size_t)mt * 128 * C_);
    Bb = (const char*)(xt + xtoff + (size_t)nt * 128 * C_);
    out = v + (size_t)b * C_ * N_;
    bias = bv;
    rstride = N_ * 2;
  }
  int t = threadIdx.x, lane = t & 63, wid = t >> 6;
  int wr = wid >> 1, wc = wid & 1;
  const f32x4 z4 = {0.f, 0.f, 0.f, 0.f};
  f32x4 acc[4][4];
  for (int i = 0; i < 4; i++)
    for (int j = 0; j < 4; j++) acc[i][j] = z4;

  char* lA = smem;
  char* lB = smem + 16384;
  for (int ko = 0; ko < C_; ko += 64) {
    __syncthreads();
    for (int i = wid; i < 16; i += 4) {
      int beta = i * 1024 + lane * 16;
      int row = beta >> 7, cb = (beta & 127) ^ ((row & 7) << 4);
      gload16(Ab + (size_t)row * 1024 + ko * 2 + cb, lA + beta);
    }
    for (int i = wid; i < 16; i += 4) {
      int beta = i * 1024 + lane * 16;
      int row = beta >> 7, cb = (beta & 127) ^ ((row & 7) << 4);
      gload16(Bb + (size_t)row * 1024 + ko * 2 + cb, lB + beta);
    }
    __syncthreads();
    for (int ks = 0; ks < 2; ks++) {
      int kb = ks * 64 + (lane >> 4) * 16;
      bf16x8 af[4], bfr[4];
      for (int fi = 0; fi < 4; fi++) {
        int row = wr * 64 + fi * 16 + (lane & 15);
        af[fi] = *(const bf16x8*)(lA + row * 128 + (kb ^ ((row & 7) << 4)));
      }
      for (int fj = 0; fj < 4; fj++) {
        int row = wc * 64 + fj * 16 + (lane & 15);
        bfr[fj] = *(const bf16x8*)(lB + row * 128 + (kb ^ ((row & 7) << 4)));
      }
      for (int fi = 0; fi < 4; fi++)
        for (int fj = 0; fj < 4; fj++)
          acc[fi][fj] = mfma16(af[fi], bfr[fj], acc[fi][fj]);
    }
  }
  __syncthreads();
  for (int fi = 0; fi < 4; fi++)
    for (int fj = 0; fj < 4; fj++) {
      int colb = wc * 64 + fj * 16 + (lane & 15);
      for (int r = 0; r < 4; r++) {
        int rowb = wr * 64 + fi * 16 + (lane >> 4) * 4 + r;
        float bva = (sel < 2) ? bias[nt * 128 + colb] : bias[mt * 128 + rowb];
        float val = acc[fi][fj][r] + bva;
        int byte = rowb * 256 + ((colb * 2) ^ ((rowb & 7) << 4));
        *(u16*)(smem + byte) = f2b(val);
      }
    }
  __syncthreads();
  for (int i = t; i < 2048; i += 256) {
    int row = i >> 4, cb = (i & 15) * 16;
    bf16x8 val = *(const bf16x8*)(smem + row * 256 + (cb ^ ((row & 7) << 4)));
    *(bf16x8*)((char*)out + (size_t)(mt * 128 + row) * rstride + nt * 256 + cb) = val;
  }
}

// ---------------- pass A: invden[bh][n] = 1/sum_m exp(scale*S[n,m]) ----------------
// [R6 config] lK rows are 256 B -> 16 slots: 4-bit swizzle (row&15)<<4 makes
// the 16-row fragment reads conflict-free (was (row&7): 2x bank duplication).
__global__ __launch_bounds__(256) void k_passA(const u16* __restrict__ qt,
                                               const u16* __restrict__ kt,
                                               float* __restrict__ invden) {
  __shared__ char lK[2][32768]; // [128 m][128 d] swizzled, x2
  int bh = blockIdx.x, nb = blockIdx.y * 64;
  int b = bh >> 2, h = bh & 3;
  const char* qb = (const char*)(qt + (size_t)b * N_ * C_ + h * DK_);
  const char* kb = (const char*)(kt + (size_t)b * N_ * C_ + h * DK_);
  int t = threadIdx.x, lane = t & 63, wid = t >> 6; // wid 0..3
  bf16x8 aq[4];
  {
    const char* qr = qb + (size_t)(nb + wid * 16 + (lane & 15)) * (C_ * 2);
    for (int ks = 0; ks < 4; ks++)
      aq[ks] = *(const bf16x8*)(qr + ks * 64 + (lane >> 4) * 16);
  }
  float sacc[4] = {0.f, 0.f, 0.f, 0.f};
  const f32x4 z4 = {0.f, 0.f, 0.f, 0.f};
  for (int i = wid; i < 32; i += 4) {
    int beta = i * 1024 + lane * 16;
    int row = beta >> 8, cb = (beta & 255) ^ ((row & 15) << 4);
    gload16(kb + (size_t)row * (C_ * 2) + cb, lK[0] + beta);
  }
  for (int mc = 0; mc < 8; mc++) {
    int cur = mc & 1;
    __syncthreads();
    if (mc < 7) {
      int mnext = (mc + 1) * 128;
      for (int i = wid; i < 32; i += 4) {
        int beta = i * 1024 + lane * 16;
        int row = beta >> 8, cb = (beta & 255) ^ ((row & 15) << 4);
        gload16(kb + (size_t)(mnext + row) * (C_ * 2) + cb, lK[cur ^ 1] + beta);
      }
    }
    for (int fj = 0; fj < 8; fj++) {
      f32x4 s = z4;
      for (int ks = 0; ks < 4; ks++) {
        int row = fj * 16 + (lane & 15);
        bf16x8 bk_ = *(const bf16x8*)(lK[cur] + row * 256 +
                                      ((ks * 64 + (lane >> 4) * 16) ^ ((row & 15) << 4)));
        s = mfma16(aq[ks], bk_, s);
      }
      for (int r = 0; r < 4; r++) sacc[r] += __expf(s[r] * kScale);
    }
  }
  for (int r = 0; r < 4; r++) {
    float vv = sacc[r];
    for (int m = 1; m < 16; m <<= 1) vv += __shfl_xor(vv, m, 64);
    sacc[r] = vv;
  }
  if ((lane & 15) == 0) {
    int n = nb + wid * 16 + (lane >> 4) * 4;
    for (int r = 0; r < 4; r++) invden[(size_t)bh * N_ + n + r] = 1.f / sacc[r];
  }
}

// ---------------- pass B: register-resident P [R6 config + 4-bit lQ swizzle] ----------------
__global__ __launch_bounds__(256) void k_passB(const u16* __restrict__ qt,
                                               const u16* __restrict__ kt,
                                               const u16* __restrict__ v,
                                               const float* __restrict__ invden,
                                               const float* __restrict__ gw,
                                               float* __restrict__ out,
                                               float* __restrict__ g) {
  __shared__ char lQ[2][16384]; // [64 n][128 d] swz (256B rows, 4-bit), x2
  __shared__ char lV[2][16384]; // [128 d][64 n] swz (128B rows, 3-bit), x2
  __shared__ float gacc[64];
  int bh = blockIdx.x, mb = blockIdx.y * 64;
  int b = bh >> 2, h = bh & 3;
  const char* qb = (const char*)(qt + (size_t)b * N_ * C_ + h * DK_);
  const char* kb = (const char*)(kt + (size_t)b * N_ * C_ + h * DK_);
  const char* vb = (const char*)(v + ((size_t)b * C_ + h * DK_) * N_);
  float* ob = out + ((size_t)b * C_ + h * DK_) * N_ + mb;
  const float* idenb = invden + (size_t)bh * N_;
  int t = threadIdx.x, lane = t & 63, wid = t >> 6; // wid 0..3
  bf16x8 bkm[4]; // wave's 16 m-rows of K (from global, fixed)
  {
    const char* kr = kb + (size_t)(mb + wid * 16 + (lane & 15)) * (C_ * 2);
    for (int ks = 0; ks < 4; ks++)
      bkm[ks] = *(const bf16x8*)(kr + ks * 64 + (lane >> 4) * 16);
  }
  if (t < 64) gacc[t] = 0.f;
  const f32x4 z4 = {0.f, 0.f, 0.f, 0.f};
  f32x4 oacc[8];
  for (int j = 0; j < 8; j++) oacc[j] = z4;

  // prologue: stage chunk 0 into buf 0
  for (int i = wid; i < 16; i += 4) {
    int beta = i * 1024 + lane * 16;
    int row = beta >> 8, cb = (beta & 255) ^ ((row & 15) << 4);
    gload16(qb + (size_t)row * (C_ * 2) + cb, lQ[0] + beta);
  }
  for (int i = wid; i < 16; i += 4) {
    int beta = i * 1024 + lane * 16;
    int row = beta >> 7, cb = (beta & 127) ^ ((row & 7) << 4);
    gload16(vb + (size_t)row * (N_ * 2) + cb, lV[0] + beta);
  }

  for (int nc = 0; nc < 16; nc++) {
    int n0 = nc * 64, cur = nc & 1;
    __syncthreads();
    if (nc < 15) {
      int nn = n0 + 64;
      for (int i = wid; i < 16; i += 4) {
        int beta = i * 1024 + lane * 16;
        int row = beta >> 8, cb = (beta & 255) ^ ((row & 15) << 4);
        gload16(qb + (size_t)(nn + row) * (C_ * 2) + cb, lQ[cur ^ 1] + beta);
      }
      for (int i = wid; i < 16; i += 4) {
        int beta = i * 1024 + lane * 16;
        int row = beta >> 7, cb = (beta & 127) ^ ((row & 7) << 4);
        gload16(vb + (size_t)row * (N_ * 2) + nn * 2 + cb, lV[cur ^ 1] + beta);
      }
    }
    // S^T phase -> register P fragments
    short4v pf[4];
    for (int fj = 0; fj < 4; fj++) {
      f32x4 s = z4;
      int qrow = fj * 16 + (lane & 15);
      const char* qr = lQ[cur] + qrow * 256;
      int qsw = (qrow & 15) << 4;
      for (int ks = 0; ks < 4; ks++) {
        bf16x8 aq = *(const bf16x8*)(qr + ((ks * 64 + (lane >> 4) * 16) ^ qsw));
        s = mfma16(aq, bkm[ks], s); // A=q(n), B=k(m) -> D[n][m]
      }
      float4 id4 = *(const float4*)(idenb + n0 + fj * 16 + (lane >> 4) * 4);
      short4v pp;
      pp[0] = (short)f2b(__expf(s[0] * kScale) * id4.x);
      pp[1] = (short)f2b(__expf(s[1] * kScale) * id4.y);
      pp[2] = (short)f2b(__expf(s[2] * kScale) * id4.z);
      pp[3] = (short)f2b(__expf(s[3] * kScale) * id4.w);
      pf[fj] = pp;
    }
    // PV phase: A=v fragments (b64 LDS reads, 2-way = free), B=pf registers
    for (int fd = 0; fd < 8; fd++) {
      int row = fd * 16 + (lane & 15);
      const char* vr = lV[cur] + row * 128;
      int sw = (row & 7) << 4;
      for (int fj = 0; fj < 4; fj++) {
        short4v av = *(const short4v*)(vr + ((fj * 32 + (lane >> 4) * 8) ^ sw));
        oacc[fd] = mfma_k16(av, pf[fj], oacc[fd]);
      }
    }
  }
  // epilogue: D[d][m] store + fused gate partial
  __syncthreads();
  float part = 0.f;
  int mcol = wid * 16 + (lane & 15);
  for (int fd = 0; fd < 8; fd++) {
    float4 gwv = *(const float4*)(gw + h * DK_ + fd * 16 + (lane >> 4) * 4);
    float gwa[4] = {gwv.x, gwv.y, gwv.z, gwv.w};
    for (int r = 0; r < 4; r++) {
      float val = oacc[fd][r];
      int d = fd * 16 + (lane >> 4) * 4 + r;
      ob[(size_t)d * N_ + mcol] = val;
      part += gwa[r] * val;
    }
  }
  atomicAdd(&gacc[mcol], part);
  __syncthreads();
  if (t < 64) atomicAdd(&g[(size_t)b * N_ + mb + t], gacc[t]);
}

// ---------------- gate apply ----------------
__global__ __launch_bounds__(256) void k_gate_apply(const float* __restrict__ g,
                                                    const float* __restrict__ gb,
                                                    float* __restrict__ out) {
  size_t i = ((size_t)blockIdx.x * 256 + threadIdx.x) * 4;
  int b = (int)(i / ((size_t)C_ * N_));
  int n = (int)(i & (N_ - 1));
  float4 gv = *(const float4*)(g + (size_t)b * N_ + n);
  float bias = gb[0];
  float4 v = *(float4*)(out + i);
  v.x *= 1.f + 1.f / (1.f + __expf(-(gv.x + bias)));
  v.y *= 1.f + 1.f / (1.f + __expf(-(gv.y + bias)));
  v.z *= 1.f + 1.f / (1.f + __expf(-(gv.z + bias)));
  v.w *= 1.f + 1.f / (1.f + __expf(-(gv.w + bias)));
  *(float4*)(out + i) = v;
}

extern "C" void kernel_launch(void* const* d_in, const int* in_sizes, int n_in,
                              void* d_out, int out_size, void* d_ws, size_t ws_size,
                              hipStream_t stream) {
  const float* x    = (const float*)d_in[0];
  const float* wq   = (const float*)d_in[1];
  const float* bq   = (const float*)d_in[2];
  const float* wk   = (const float*)d_in[3];
  const float* bk   = (const float*)d_in[4];
  const float* wv   = (const float*)d_in[5];
  const float* bv   = (const float*)d_in[6];
  const float* fc1w = (const float*)d_in[7];
  const float* fc1b = (const float*)d_in[8];
  const float* fc2w = (const float*)d_in[9];
  const float* fc2b = (const float*)d_in[10];
  const float* gw   = (const float*)d_in[11];
  const float* gb   = (const float*)d_in[12];
  float* out = (float*)d_out;
  char* ws = (char*)d_ws;

  float* p   = (float*)(ws + OFF_P);
  float* ssc = (float*)(ws + OFF_SS);
  u16* wb  = (u16*)(ws + OFF_WB);
  u16* xt  = (u16*)(ws + OFF_XT);
  u16* qt  = (u16*)(ws + OFF_QT);
  u16* kt  = (u16*)(ws + OFF_KT);
  u16* v   = (u16*)(ws + OFF_V);
  float* den = (float*)(ws + OFF_DEN);
  float* g   = (float*)(ws + OFF_G);

  k_pool<<<B_ * C_, 64, 0, stream>>>(x, p);
  k_castw_zero<<<800, 256, 0, stream>>>(wq, wk, wv, wb, g);
  k_se<<<B_, 256, 0, stream>>>(p, fc1w, fc1b, fc2w, fc2b, ssc);
  k_xt<<<dim3(16, 8, B_), 256, 0, stream>>>(x, ssc, xt);
  k_qkv<<<dim3(32, B_ * 3), 256, 0, stream>>>(xt, wb, bq, bk, bv, qt, kt, v);
  k_passA<<<dim3(32, 16), 256, 0, stream>>>(qt, kt, den);
  k_passB<<<dim3(32, 16), 256, 0, stream>>>(qt, kt, v, den, gw, out, g);
  k_gate_apply<<<B_ * C_ * N_ / 1024, 256, 0, stream>>>(g, gb, out);
}

// Round 13
// 120.295 us; speedup vs baseline: 1.1816x; 1.0019x over previous
//
#include <hip/hip_runtime.h>
#include <hip/hip_bf16.h>

#define B_ 8
#define C_ 512
#define N_ 1024
#define HEADS_ 4
#define DK_ 128
#define R_ 128

typedef float f32x4 __attribute__((ext_vector_type(4)));
typedef __bf16 bf16x8 __attribute__((ext_vector_type(8)));
typedef short short4v __attribute__((ext_vector_type(4)));
typedef unsigned short u16;

constexpr float kScale = 0.08838834764831845f; // 1/sqrt(128)

// ---- workspace layout (bytes); ws_size = 256 MiB ----
#define OFF_P   0u
#define OFF_SS  16384u
#define OFF_WB  32768u
#define OFF_XT  1605632u
#define OFF_QT  9994240u
#define OFF_KT  18382848u
#define OFF_V   26771456u
#define OFF_DEN 35160064u                // invden [B*H][N] f32    128KB
#define OFF_G   35291136u                // gate dot [B][N] f32    32KB
#define OFF_O1  35323904u                // o half-1 [B][C][N] f32 16MB
#define OFF_E   52101120u                // E^T [B*H][m=N][n=N] bf16 64MB

__device__ __forceinline__ u16 f2b(float f) {
  __hip_bfloat16 h = __float2bfloat16(f);
  return __builtin_bit_cast(u16, h);
}
__device__ __forceinline__ float b2f(u16 u) {
  return __builtin_bit_cast(float, (unsigned)u << 16);
}

typedef const __attribute__((address_space(1))) unsigned int* gptr_t;
typedef __attribute__((address_space(3))) unsigned int* lptr_t;
__device__ __forceinline__ void gload16(const void* g, void* l) {
  __builtin_amdgcn_global_load_lds((gptr_t)g, (lptr_t)l, 16, 0, 0);
}

__device__ __forceinline__ f32x4 mfma16(bf16x8 a, bf16x8 b, f32x4 c) {
  return __builtin_amdgcn_mfma_f32_16x16x32_bf16(a, b, c, 0, 0, 0);
}

// ---------------- pool ----------------
__global__ __launch_bounds__(64) void k_pool(const float* __restrict__ x,
                                             float* __restrict__ p) {
  int bc = blockIdx.x, lane = threadIdx.x;
  const float4* row = (const float4*)(x + (size_t)bc * N_);
  float s = 0.f;
  for (int i = lane; i < N_ / 4; i += 64) {
    float4 t = row[i];
    s += t.x + t.y + t.z + t.w;
  }
  for (int o = 32; o > 0; o >>= 1) s += __shfl_down(s, o, 64);
  if (lane == 0) p[bc] = s * (1.0f / N_);
}

// ---------------- SE MLP ----------------
__global__ __launch_bounds__(256) void k_se(const float* __restrict__ p,
                                            const float* __restrict__ fc1w,
                                            const float* __restrict__ fc1b,
                                            const float* __restrict__ fc2w,
                                            const float* __restrict__ fc2b,
                                            float* __restrict__ ss) {
  __shared__ float pl[C_];
  __shared__ float f1[R_];
  int b = blockIdx.x, t = threadIdx.x;
  for (int c = t; c < C_; c += 256) pl[c] = p[b * C_ + c];
  __syncthreads();
  if (t < R_) {
    float a = fc1b[t];
    for (int c = 0; c < C_; c++) a += pl[c] * fc1w[t * C_ + c];
    f1[t] = fmaxf(a, 0.f);
  }
  __syncthreads();
  for (int c = t; c < C_; c += 256) {
    float a = fc2b[c];
    for (int j = 0; j < R_; j++) a += f1[j] * fc2w[c * R_ + j];
    ss[b * C_ + c] = 1.f + 1.f / (1.f + __expf(-a));
  }
}

// ---------------- cast weights + zero g ----------------
__global__ __launch_bounds__(256) void k_castw_zero(const float* __restrict__ wq,
                                                    const float* __restrict__ wk,
                                                    const float* __restrict__ wv,
                                                    u16* __restrict__ wb,
                                                    float* __restrict__ g) {
  int bid = blockIdx.x;
  if (bid >= 768) {
    g[(bid - 768) * 256 + threadIdx.x] = 0.f;
    return;
  }
  int i = bid * 256 + threadIdx.x;
  int idx = i * 4;
  const float* srcs[3] = {wq, wk, wv};
  int w = idx / (C_ * C_), off = idx % (C_ * C_);
  float4 v = *(const float4*)(srcs[w] + off);
  u16* d = wb + idx;
  d[0] = f2b(v.x); d[1] = f2b(v.y); d[2] = f2b(v.z); d[3] = f2b(v.w);
}

// ---------------- x1^T ----------------
__global__ __launch_bounds__(256) void k_xt(const float* __restrict__ x,
                                            const float* __restrict__ ss,
                                            u16* __restrict__ xt) {
  int b = blockIdx.z, c0 = blockIdx.y * 64, n0 = blockIdx.x * 64;
  __shared__ float tile[64][65];
  int t = threadIdx.x;
  int cr = t >> 4, nc4 = (t & 15) * 4;
  for (int j = 0; j < 4; j++) {
    int c = cr + j * 16;
    float sc = ss[b * C_ + c0 + c];
    float4 v = *(const float4*)(x + ((size_t)b * C_ + c0 + c) * N_ + n0 + nc4);
    tile[c][nc4 + 0] = v.x * sc;
    tile[c][nc4 + 1] = v.y * sc;
    tile[c][nc4 + 2] = v.z * sc;
    tile[c][nc4 + 3] = v.w * sc;
  }
  __syncthreads();
  int nr = t >> 2, cc = (t & 3) * 16;
  u16 ov[16];
  for (int m = 0; m < 16; m++) ov[m] = f2b(tile[cc + m][nr]);
  u16* dst = xt + ((size_t)b * N_ + n0 + nr) * C_ + c0 + cc;
  for (int m = 0; m < 16; m++) dst[m] = ov[m];
}

// ---------------- QKV GEMM ----------------
__global__ __launch_bounds__(256) void k_qkv(const u16* __restrict__ xt,
                                             const u16* __restrict__ wb,
                                             const float* __restrict__ bq,
                                             const float* __restrict__ bk,
                                             const float* __restrict__ bv,
                                             u16* __restrict__ qt,
                                             u16* __restrict__ kt,
                                             u16* __restrict__ v) {
  __shared__ char smem[32768];
  int b = blockIdx.y / 3, sel = blockIdx.y % 3;
  int tile = blockIdx.x;
  const char *Ab, *Bb;
  u16* out;
  const float* bias;
  int mt, nt, rstride;
  size_t xtoff = (size_t)b * N_ * C_;
  if (sel < 2) {
    mt = tile & 7; nt = tile >> 3;
    Ab = (const char*)(xt + xtoff + (size_t)mt * 128 * C_);
    Bb = (const char*)(wb + (size_t)sel * C_ * C_ + (size_t)nt * 128 * C_);
    out = (sel ? kt : qt) + xtoff;
    bias = sel ? bk : bq;
    rstride = C_ * 2;
  } else {
    mt = tile & 3; nt = tile >> 2;
    Ab = (const char*)(wb + (size_t)2 * C_ * C_ + (size_t)mt * 128 * C_);
    Bb = (const char*)(xt + xtoff + (size_t)nt * 128 * C_);
    out = v + (size_t)b * C_ * N_;
    bias = bv;
    rstride = N_ * 2;
  }
  int t = threadIdx.x, lane = t & 63, wid = t >> 6;
  int wr = wid >> 1, wc = wid & 1;
  const f32x4 z4 = {0.f, 0.f, 0.f, 0.f};
  f32x4 acc[4][4];
  for (int i = 0; i < 4; i++)
    for (int j = 0; j < 4; j++) acc[i][j] = z4;

  char* lA = smem;
  char* lB = smem + 16384;
  for (int ko = 0; ko < C_; ko += 64) {
    __syncthreads();
    for (int i = wid; i < 16; i += 4) {
      int beta = i * 1024 + lane * 16;
      int row = beta >> 7, cb = (beta & 127) ^ ((row & 7) << 4);
      gload16(Ab + (size_t)row * 1024 + ko * 2 + cb, lA + beta);
    }
    for (int i = wid; i < 16; i += 4) {
      int beta = i * 1024 + lane * 16;
      int row = beta >> 7, cb = (beta & 127) ^ ((row & 7) << 4);
      gload16(Bb + (size_t)row * 1024 + ko * 2 + cb, lB + beta);
    }
    __syncthreads();
    for (int ks = 0; ks < 2; ks++) {
      int kb = ks * 64 + (lane >> 4) * 16;
      bf16x8 af[4], bfr[4];
      for (int fi = 0; fi < 4; fi++) {
        int row = wr * 64 + fi * 16 + (lane & 15);
        af[fi] = *(const bf16x8*)(lA + row * 128 + (kb ^ ((row & 7) << 4)));
      }
      for (int fj = 0; fj < 4; fj++) {
        int row = wc * 64 + fj * 16 + (lane & 15);
        bfr[fj] = *(const bf16x8*)(lB + row * 128 + (kb ^ ((row & 7) << 4)));
      }
      for (int fi = 0; fi < 4; fi++)
        for (int fj = 0; fj < 4; fj++)
          acc[fi][fj] = mfma16(af[fi], bfr[fj], acc[fi][fj]);
    }
  }
  __syncthreads();
  for (int fi = 0; fi < 4; fi++)
    for (int fj = 0; fj < 4; fj++) {
      int colb = wc * 64 + fj * 16 + (lane & 15);
      for (int r = 0; r < 4; r++) {
        int rowb = wr * 64 + fi * 16 + (lane >> 4) * 4 + r;
        float bva = (sel < 2) ? bias[nt * 128 + colb] : bias[mt * 128 + rowb];
        float val = acc[fi][fj][r] + bva;
        int byte = rowb * 256 + ((colb * 2) ^ ((rowb & 7) << 4));
        *(u16*)(smem + byte) = f2b(val);
      }
    }
  __syncthreads();
  for (int i = t; i < 2048; i += 256) {
    int row = i >> 4, cb = (i & 15) * 16;
    bf16x8 val = *(const bf16x8*)(smem + row * 256 + (cb ^ ((row & 7) << 4)));
    *(bf16x8*)((char*)out + (size_t)(mt * 128 + row) * rstride + nt * 256 + cb) = val;
  }
}

// ---------------- pass A: E^T[m][n] = exp(scale*S[n,m]) (bf16) + invden ----------------
// Swapped operands: mfma(A=k(m rows), B=q(n rows)) -> D[m][n]; lane holds one
// n-column -> den is lane-local + 2 shuffles. E restaged via LDS, b128 stores.
__global__ __launch_bounds__(256) void k_passA(const u16* __restrict__ qt,
                                               const u16* __restrict__ kt,
                                               u16* __restrict__ et,
                                               float* __restrict__ invden) {
  __shared__ char lK[2][32768]; // [128 m][128 d], 256B rows, 4-bit swz, x2
  __shared__ char lE[16384];    // [128 m][64 n] u16, 128B rows, 3-bit swz
  int bh = blockIdx.x, nb = blockIdx.y * 64;
  int b = bh >> 2, h = bh & 3;
  const char* qb = (const char*)(qt + (size_t)b * N_ * C_ + h * DK_);
  const char* kb = (const char*)(kt + (size_t)b * N_ * C_ + h * DK_);
  char* etb = (char*)(et + (size_t)bh * N_ * N_);
  int t = threadIdx.x, lane = t & 63, wid = t >> 6; // wid 0..3
  // B operand: wave's 16 q-rows (n)
  bf16x8 bq[4];
  {
    const char* qr = qb + (size_t)(nb + wid * 16 + (lane & 15)) * (C_ * 2);
    for (int ks = 0; ks < 4; ks++)
      bq[ks] = *(const bf16x8*)(qr + ks * 64 + (lane >> 4) * 16);
  }
  float dpart = 0.f;
  const f32x4 z4 = {0.f, 0.f, 0.f, 0.f};
  for (int i = wid; i < 32; i += 4) {
    int beta = i * 1024 + lane * 16;
    int row = beta >> 8, cb = (beta & 255) ^ ((row & 15) << 4);
    gload16(kb + (size_t)row * (C_ * 2) + cb, lK[0] + beta);
  }
  int nloc2 = (wid * 16 + (lane & 15)) * 2; // lE byte col
  for (int mc = 0; mc < 8; mc++) {
    int cur = mc & 1;
    __syncthreads(); // lK[cur] staged; prior lE store-reads done
    if (mc < 7) {
      int mnext = (mc + 1) * 128;
      for (int i = wid; i < 32; i += 4) {
        int beta = i * 1024 + lane * 16;
        int row = beta >> 8, cb = (beta & 255) ^ ((row & 15) << 4);
        gload16(kb + (size_t)(mnext + row) * (C_ * 2) + cb, lK[cur ^ 1] + beta);
      }
    }
    for (int fj = 0; fj < 8; fj++) {
      f32x4 s = z4;
      for (int ks = 0; ks < 4; ks++) {
        int row = fj * 16 + (lane & 15);
        bf16x8 ak = *(const bf16x8*)(lK[cur] + row * 256 +
                                     ((ks * 64 + (lane >> 4) * 16) ^ ((row & 15) << 4)));
        s = mfma16(ak, bq[ks], s); // A=k(m), B=q(n) -> D[m][n]
      }
      for (int r = 0; r < 4; r++) {
        float e = __expf(s[r] * kScale);
        dpart += e;
        int m = fj * 16 + (lane >> 4) * 4 + r;
        *(u16*)(lE + m * 128 + (nloc2 ^ ((m & 7) << 4))) = f2b(e);
      }
    }
    __syncthreads(); // lE complete
    for (int i = t; i < 1024; i += 256) {
      int row = i >> 3, c16 = (i & 7) * 16;
      bf16x8 val = *(const bf16x8*)(lE + row * 128 + (c16 ^ ((row & 7) << 4)));
      *(bf16x8*)(etb + (size_t)(mc * 128 + row) * (N_ * 2) + nb * 2 + c16) = val;
    }
  }
  // den[n] for lane's fixed n: combine the 4 lane-groups
  dpart += __shfl_xor(dpart, 16, 64);
  dpart += __shfl_xor(dpart, 32, 64);
  if (lane < 16)
    invden[(size_t)bh * N_ + nb + wid * 16 + lane] = 1.f / dpart;
}

// ---------------- vscale: v[b][c][n] *= invden[b*4 + c/128][n] (in place) ----------------
__global__ __launch_bounds__(256) void k_vscale(u16* __restrict__ v,
                                                const float* __restrict__ invden) {
  size_t i = ((size_t)blockIdx.x * 256 + threadIdx.x) * 8;
  int n = (int)(i & (N_ - 1));
  int bc = (int)(i >> 10);
  int b = bc >> 9, c = bc & 511, h = c >> 7;
  const float* iv = invden + ((size_t)(b * 4 + h)) * N_ + n;
  float4 iv0 = *(const float4*)(iv);
  float4 iv1 = *(const float4*)(iv + 4);
  u16* p = v + i;
  short4v a = *(short4v*)p, bb = *(short4v*)(p + 4);
  u16 o[8];
  o[0] = f2b(b2f((u16)a[0]) * iv0.x);
  o[1] = f2b(b2f((u16)a[1]) * iv0.y);
  o[2] = f2b(b2f((u16)a[2]) * iv0.z);
  o[3] = f2b(b2f((u16)a[3]) * iv0.w);
  o[4] = f2b(b2f((u16)bb[0]) * iv1.x);
  o[5] = f2b(b2f((u16)bb[1]) * iv1.y);
  o[6] = f2b(b2f((u16)bb[2]) * iv1.z);
  o[7] = f2b(b2f((u16)bb[3]) * iv1.w);
  short4v r0 = {(short)o[0], (short)o[1], (short)o[2], (short)o[3]};
  short4v r1 = {(short)o[4], (short)o[5], (short)o[6], (short)o[7]};
  *(short4v*)p = r0;
  *(short4v*)(p + 4) = r1;
}

// ---------------- pass B: pure GEMM o = v' . E^T + gate dot ----------------
// grid (bh, 8 m-tiles of 128, 2 n-halves). A = v' [128 d][n], B = E^T [m][n],
// both row-stride 2048 B. Half 0 -> out, half 1 -> o1.
__global__ __launch_bounds__(256) void k_passB(const u16* __restrict__ v,
                                               const u16* __restrict__ et,
                                               const float* __restrict__ gw,
                                               float* __restrict__ out0,
                                               float* __restrict__ o1,
                                               float* __restrict__ g) {
  __shared__ char smem[32768];
  __shared__ float gacc[128];
  int bh = blockIdx.x, mt = blockIdx.y, nh = blockIdx.z;
  int b = bh >> 2, h = bh & 3;
  const char* Ab = (const char*)(v + ((size_t)b * C_ + h * DK_) * N_) + nh * 1024;
  const char* Bb = (const char*)(et + (size_t)bh * N_ * N_ + (size_t)mt * 128 * N_) + nh * 1024;
  float* ob = (nh ? o1 : out0) + ((size_t)b * C_ + h * DK_) * N_ + mt * 128;
  int t = threadIdx.x, lane = t & 63, wid = t >> 6;
  int wr = wid >> 1, wc = wid & 1;
  if (t < 128) gacc[t] = 0.f;
  const f32x4 z4 = {0.f, 0.f, 0.f, 0.f};
  f32x4 acc[4][4];
  for (int i = 0; i < 4; i++)
    for (int j = 0; j < 4; j++) acc[i][j] = z4;

  char* lA = smem;
  char* lB = smem + 16384;
  for (int ko = 0; ko < 512; ko += 64) {
    __syncthreads();
    for (int i = wid; i < 16; i += 4) {
      int beta = i * 1024 + lane * 16;
      int row = beta >> 7, cb = (beta & 127) ^ ((row & 7) << 4);
      gload16(Ab + (size_t)row * 2048 + ko * 2 + cb, lA + beta);
    }
    for (int i = wid; i < 16; i += 4) {
      int beta = i * 1024 + lane * 16;
      int row = beta >> 7, cb = (beta & 127) ^ ((row & 7) << 4);
      gload16(Bb + (size_t)row * 2048 + ko * 2 + cb, lB + beta);
    }
    __syncthreads();
    for (int ks = 0; ks < 2; ks++) {
      int kb = ks * 64 + (lane >> 4) * 16;
      bf16x8 af[4], bfr[4];
      for (int fi = 0; fi < 4; fi++) {
        int row = wr * 64 + fi * 16 + (lane & 15);
        af[fi] = *(const bf16x8*)(lA + row * 128 + (kb ^ ((row & 7) << 4)));
      }
      for (int fj = 0; fj < 4; fj++) {
        int row = wc * 64 + fj * 16 + (lane & 15);
        bfr[fj] = *(const bf16x8*)(lB + row * 128 + (kb ^ ((row & 7) << 4)));
      }
      for (int fi = 0; fi < 4; fi++)
        for (int fj = 0; fj < 4; fj++)
          acc[fi][fj] = mfma16(af[fi], bfr[fj], acc[fi][fj]);
    }
  }
  // epilogue: f32 stores + gate partial (D[d][m]: d rows, m cols)
  for (int fj = 0; fj < 4; fj++) {
    int mcol = wc * 64 + fj * 16 + (lane & 15);
    float part = 0.f;
    for (int fi = 0; fi < 4; fi++) {
      int d = wr * 64 + fi * 16 + (lane >> 4) * 4;
      float4 gwv = *(const float4*)(gw + h * DK_ + d);
      float ga[4] = {gwv.x, gwv.y, gwv.z, gwv.w};
      for (int r = 0; r < 4; r++) {
        float val = acc[fi][fj][r];
        ob[(size_t)(d + r) * N_ + mcol] = val;
        part += ga[r] * val;
      }
    }
    atomicAdd(&gacc[mcol], part);
  }
  __syncthreads();
  if (t < 128) atomicAdd(&g[(size_t)b * N_ + mt * 128 + t], gacc[t]);
}

// ---------------- gate apply: out = (out + o1) * (1 + sigmoid(g + gb)) ----------------
__global__ __launch_bounds__(256) void k_gate_apply(const float* __restrict__ g,
                                                    const float* __restrict__ gb,
                                                    const float* __restrict__ o1,
                                                    float* __restrict__ out) {
  size_t i = ((size_t)blockIdx.x * 256 + threadIdx.x) * 4;
  int b = (int)(i / ((size_t)C_ * N_));
  int n = (int)(i & (N_ - 1));
  float4 gv = *(const float4*)(g + (size_t)b * N_ + n);
  float bias = gb[0];
  float4 v0 = *(float4*)(out + i);
  float4 v1 = *(const float4*)(o1 + i);
  float ox = v0.x + v1.x, oy = v0.y + v1.y, oz = v0.z + v1.z, ow = v0.w + v1.w;
  ox *= 1.f + 1.f / (1.f + __expf(-(gv.x + bias)));
  oy *= 1.f + 1.f / (1.f + __expf(-(gv.y + bias)));
  oz *= 1.f + 1.f / (1.f + __expf(-(gv.z + bias)));
  ow *= 1.f + 1.f / (1.f + __expf(-(gv.w + bias)));
  float4 r = {ox, oy, oz, ow};
  *(float4*)(out + i) = r;
}

extern "C" void kernel_launch(void* const* d_in, const int* in_sizes, int n_in,
                              void* d_out, int out_size, void* d_ws, size_t ws_size,
                              hipStream_t stream) {
  const float* x    = (const float*)d_in[0];
  const float* wq   = (const float*)d_in[1];
  const float* bq   = (const float*)d_in[2];
  const float* wk   = (const float*)d_in[3];
  const float* bk   = (const float*)d_in[4];
  const float* wv   = (const float*)d_in[5];
  const float* bv   = (const float*)d_in[6];
  const float* fc1w = (const float*)d_in[7];
  const float* fc1b = (const float*)d_in[8];
  const float* fc2w = (const float*)d_in[9];
  const float* fc2b = (const float*)d_in[10];
  const float* gw   = (const float*)d_in[11];
  const float* gb   = (const float*)d_in[12];
  float* out = (float*)d_out;
  char* ws = (char*)d_ws;

  float* p   = (float*)(ws + OFF_P);
  float* ssc = (float*)(ws + OFF_SS);
  u16* wb  = (u16*)(ws + OFF_WB);
  u16* xt  = (u16*)(ws + OFF_XT);
  u16* qt  = (u16*)(ws + OFF_QT);
  u16* kt  = (u16*)(ws + OFF_KT);
  u16* v   = (u16*)(ws + OFF_V);
  float* den = (float*)(ws + OFF_DEN);
  float* g   = (float*)(ws + OFF_G);
  float* o1  = (float*)(ws + OFF_O1);
  u16* et  = (u16*)(ws + OFF_E);

  k_pool<<<B_ * C_, 64, 0, stream>>>(x, p);
  k_castw_zero<<<800, 256, 0, stream>>>(wq, wk, wv, wb, g);
  k_se<<<B_, 256, 0, stream>>>(p, fc1w, fc1b, fc2w, fc2b, ssc);
  k_xt<<<dim3(16, 8, B_), 256, 0, stream>>>(x, ssc, xt);
  k_qkv<<<dim3(32, B_ * 3), 256, 0, stream>>>(xt, wb, bq, bk, bv, qt, kt, v);
  k_passA<<<dim3(32, 16), 256, 0, stream>>>(qt, kt, et, den);
  k_vscale<<<2048, 256, 0, stream>>>(v, den);
  k_passB<<<dim3(32, 8, 2), 256, 0, stream>>>(v, et, gw, out, o1, g);
  k_gate_apply<<<B_ * C_ * N_ / 1024, 256, 0, stream>>>(g, gb, o1, out);
}

// Round 14
// 119.506 us; speedup vs baseline: 1.1894x; 1.0066x over previous
//
#include <hip/hip_runtime.h>
#include <hip/hip_bf16.h>

#define B_ 8
#define C_ 512
#define N_ 1024
#define HEADS_ 4
#define DK_ 128
#define R_ 128

typedef float f32x4 __attribute__((ext_vector_type(4)));
typedef __bf16 bf16x8 __attribute__((ext_vector_type(8)));
typedef short short4v __attribute__((ext_vector_type(4)));
typedef short short8v __attribute__((ext_vector_type(8)));
typedef unsigned short u16;

constexpr float kScale = 0.08838834764831845f; // 1/sqrt(128)

// ---- workspace layout (bytes); ws_size = 256 MiB ----
#define OFF_P   0u
#define OFF_SS  16384u
#define OFF_WB  32768u
#define OFF_XT  1605632u
#define OFF_QT  9994240u
#define OFF_KT  18382848u
#define OFF_V   26771456u
#define OFF_DEN 35160064u                // den [B*H][N] f32 (atomic) 128KB
#define OFF_G   35291136u                // gate dot [B][N] f32    32KB
#define OFF_O1  35323904u                // o half-1 [B][C][N] f32 16MB
#define OFF_E   52101120u                // E^T [B*H][m=N][n=N] bf16 64MB

__device__ __forceinline__ u16 f2b(float f) {
  __hip_bfloat16 h = __float2bfloat16(f);
  return __builtin_bit_cast(u16, h);
}
__device__ __forceinline__ float b2f(u16 u) {
  return __builtin_bit_cast(float, (unsigned)u << 16);
}

typedef const __attribute__((address_space(1))) unsigned int* gptr_t;
typedef __attribute__((address_space(3))) unsigned int* lptr_t;
__device__ __forceinline__ void gload16(const void* g, void* l) {
  __builtin_amdgcn_global_load_lds((gptr_t)g, (lptr_t)l, 16, 0, 0);
}

__device__ __forceinline__ f32x4 mfma16(bf16x8 a, bf16x8 b, f32x4 c) {
  return __builtin_amdgcn_mfma_f32_16x16x32_bf16(a, b, c, 0, 0, 0);
}

// ---------------- pool ----------------
__global__ __launch_bounds__(64) void k_pool(const float* __restrict__ x,
                                             float* __restrict__ p) {
  int bc = blockIdx.x, lane = threadIdx.x;
  const float4* row = (const float4*)(x + (size_t)bc * N_);
  float s = 0.f;
  for (int i = lane; i < N_ / 4; i += 64) {
    float4 t = row[i];
    s += t.x + t.y + t.z + t.w;
  }
  for (int o = 32; o > 0; o >>= 1) s += __shfl_down(s, o, 64);
  if (lane == 0) p[bc] = s * (1.0f / N_);
}

// ---------------- SE MLP ----------------
__global__ __launch_bounds__(256) void k_se(const float* __restrict__ p,
                                            const float* __restrict__ fc1w,
                                            const float* __restrict__ fc1b,
                                            const float* __restrict__ fc2w,
                                            const float* __restrict__ fc2b,
                                            float* __restrict__ ss) {
  __shared__ float pl[C_];
  __shared__ float f1[R_];
  int b = blockIdx.x, t = threadIdx.x;
  for (int c = t; c < C_; c += 256) pl[c] = p[b * C_ + c];
  __syncthreads();
  if (t < R_) {
    float a = fc1b[t];
    for (int c = 0; c < C_; c++) a += pl[c] * fc1w[t * C_ + c];
    f1[t] = fmaxf(a, 0.f);
  }
  __syncthreads();
  for (int c = t; c < C_; c += 256) {
    float a = fc2b[c];
    for (int j = 0; j < R_; j++) a += f1[j] * fc2w[c * R_ + j];
    ss[b * C_ + c] = 1.f + 1.f / (1.f + __expf(-a));
  }
}

// ---------------- cast weights + zero g + zero den ----------------
__global__ __launch_bounds__(256) void k_castw_zero(const float* __restrict__ wq,
                                                    const float* __restrict__ wk,
                                                    const float* __restrict__ wv,
                                                    u16* __restrict__ wb,
                                                    float* __restrict__ g,
                                                    float* __restrict__ den) {
  int bid = blockIdx.x;
  if (bid >= 800) {
    den[(bid - 800) * 256 + threadIdx.x] = 0.f;
    return;
  }
  if (bid >= 768) {
    g[(bid - 768) * 256 + threadIdx.x] = 0.f;
    return;
  }
  int i = bid * 256 + threadIdx.x;
  int idx = i * 4;
  const float* srcs[3] = {wq, wk, wv};
  int w = idx / (C_ * C_), off = idx % (C_ * C_);
  float4 v = *(const float4*)(srcs[w] + off);
  u16* d = wb + idx;
  d[0] = f2b(v.x); d[1] = f2b(v.y); d[2] = f2b(v.z); d[3] = f2b(v.w);
}

// ---------------- x1^T (vectorized 16B stores) ----------------
__global__ __launch_bounds__(256) void k_xt(const float* __restrict__ x,
                                            const float* __restrict__ ss,
                                            u16* __restrict__ xt) {
  int b = blockIdx.z, c0 = blockIdx.y * 64, n0 = blockIdx.x * 64;
  __shared__ float tile[64][65];
  int t = threadIdx.x;
  int cr = t >> 4, nc4 = (t & 15) * 4;
  for (int j = 0; j < 4; j++) {
    int c = cr + j * 16;
    float sc = ss[b * C_ + c0 + c];
    float4 v = *(const float4*)(x + ((size_t)b * C_ + c0 + c) * N_ + n0 + nc4);
    tile[c][nc4 + 0] = v.x * sc;
    tile[c][nc4 + 1] = v.y * sc;
    tile[c][nc4 + 2] = v.z * sc;
    tile[c][nc4 + 3] = v.w * sc;
  }
  __syncthreads();
  int nr = t >> 2, cc = (t & 3) * 16;
  short8v s0, s1;
  for (int m = 0; m < 8; m++) {
    s0[m] = (short)f2b(tile[cc + m][nr]);
    s1[m] = (short)f2b(tile[cc + 8 + m][nr]);
  }
  u16* dst = xt + ((size_t)b * N_ + n0 + nr) * C_ + c0 + cc;
  *(short8v*)dst = s0;
  *(short8v*)(dst + 8) = s1;
}

// ---------------- QKV GEMM ----------------
__global__ __launch_bounds__(256) void k_qkv(const u16* __restrict__ xt,
                                             const u16* __restrict__ wb,
                                             const float* __restrict__ bq,
                                             const float* __restrict__ bk,
                                             const float* __restrict__ bv,
                                             u16* __restrict__ qt,
                                             u16* __restrict__ kt,
                                             u16* __restrict__ v) {
  __shared__ char smem[32768];
  int b = blockIdx.y / 3, sel = blockIdx.y % 3;
  int tile = blockIdx.x;
  const char *Ab, *Bb;
  u16* out;
  const float* bias;
  int mt, nt, rstride;
  size_t xtoff = (size_t)b * N_ * C_;
  if (sel < 2) {
    mt = tile & 7; nt = tile >> 3;
    Ab = (const char*)(xt + xtoff + (size_t)mt * 128 * C_);
    Bb = (const char*)(wb + (size_t)sel * C_ * C_ + (size_t)nt * 128 * C_);
    out = (sel ? kt : qt) + xtoff;
    bias = sel ? bk : bq;
    rstride = C_ * 2;
  } else {
    mt = tile & 3; nt = tile >> 2;
    Ab = (const char*)(wb + (size_t)2 * C_ * C_ + (size_t)mt * 128 * C_);
    Bb = (const char*)(xt + xtoff + (size_t)nt * 128 * C_);
    out = v + (size_t)b * C_ * N_;
    bias = bv;
    rstride = N_ * 2;
  }
  int t = threadIdx.x, lane = t & 63, wid = t >> 6;
  int wr = wid >> 1, wc = wid & 1;
  const f32x4 z4 = {0.f, 0.f, 0.f, 0.f};
  f32x4 acc[4][4];
  for (int i = 0; i < 4; i++)
    for (int j = 0; j < 4; j++) acc[i][j] = z4;

  char* lA = smem;
  char* lB = smem + 16384;
  for (int ko = 0; ko < C_; ko += 64) {
    __syncthreads();
    for (int i = wid; i < 16; i += 4) {
      int beta = i * 1024 + lane * 16;
      int row = beta >> 7, cb = (beta & 127) ^ ((row & 7) << 4);
      gload16(Ab + (size_t)row * 1024 + ko * 2 + cb, lA + beta);
    }
    for (int i = wid; i < 16; i += 4) {
      int beta = i * 1024 + lane * 16;
      int row = beta >> 7, cb = (beta & 127) ^ ((row & 7) << 4);
      gload16(Bb + (size_t)row * 1024 + ko * 2 + cb, lB + beta);
    }
    __syncthreads();
    for (int ks = 0; ks < 2; ks++) {
      int kb = ks * 64 + (lane >> 4) * 16;
      bf16x8 af[4], bfr[4];
      for (int fi = 0; fi < 4; fi++) {
        int row = wr * 64 + fi * 16 + (lane & 15);
        af[fi] = *(const bf16x8*)(lA + row * 128 + (kb ^ ((row & 7) << 4)));
      }
      for (int fj = 0; fj < 4; fj++) {
        int row = wc * 64 + fj * 16 + (lane & 15);
        bfr[fj] = *(const bf16x8*)(lB + row * 128 + (kb ^ ((row & 7) << 4)));
      }
      for (int fi = 0; fi < 4; fi++)
        for (int fj = 0; fj < 4; fj++)
          acc[fi][fj] = mfma16(af[fi], bfr[fj], acc[fi][fj]);
    }
  }
  __syncthreads();
  for (int fi = 0; fi < 4; fi++)
    for (int fj = 0; fj < 4; fj++) {
      int colb = wc * 64 + fj * 16 + (lane & 15);
      for (int r = 0; r < 4; r++) {
        int rowb = wr * 64 + fi * 16 + (lane >> 4) * 4 + r;
        float bva = (sel < 2) ? bias[nt * 128 + colb] : bias[mt * 128 + rowb];
        float val = acc[fi][fj][r] + bva;
        int byte = rowb * 256 + ((colb * 2) ^ ((rowb & 7) << 4));
        *(u16*)(smem + byte) = f2b(val);
      }
    }
  __syncthreads();
  for (int i = t; i < 2048; i += 256) {
    int row = i >> 4, cb = (i & 15) * 16;
    bf16x8 val = *(const bf16x8*)(smem + row * 256 + (cb ^ ((row & 7) << 4)));
    *(bf16x8*)((char*)out + (size_t)(mt * 128 + row) * rstride + nt * 256 + cb) = val;
  }
}

// ---------------- pass A: E^T[m][n] = exp(scale*S[n,m]) (bf16) + den (atomic) ----------------
// grid (bh, 16 nb of 64, 2 m-halves) = 1024 blocks; 64-m chunks -> LDS 40KB
// -> 4 blocks/CU. Swapped operands (A=k(m), B=q(n)) -> D[m][n]; den lane-local.
__global__ __launch_bounds__(256) void k_passA(const u16* __restrict__ qt,
                                               const u16* __restrict__ kt,
                                               u16* __restrict__ et,
                                               float* __restrict__ den) {
  __shared__ char lK[2][16384]; // [64 m][128 d], 256B rows, 4-bit swz, x2
  __shared__ char lE[8192];     // [64 m][64 n] u16, 128B rows, 3-bit swz
  int bh = blockIdx.x, nb = blockIdx.y * 64, mh = blockIdx.z;
  int b = bh >> 2, h = bh & 3;
  const char* qb = (const char*)(qt + (size_t)b * N_ * C_ + h * DK_);
  const char* kb = (const char*)(kt + (size_t)b * N_ * C_ + h * DK_);
  char* etb = (char*)(et + (size_t)bh * N_ * N_);
  int t = threadIdx.x, lane = t & 63, wid = t >> 6; // wid 0..3
  // B operand: wave's 16 q-rows (n)
  bf16x8 bq[4];
  {
    const char* qr = qb + (size_t)(nb + wid * 16 + (lane & 15)) * (C_ * 2);
    for (int ks = 0; ks < 4; ks++)
      bq[ks] = *(const bf16x8*)(qr + ks * 64 + (lane >> 4) * 16);
  }
  float dpart = 0.f;
  const f32x4 z4 = {0.f, 0.f, 0.f, 0.f};
  int m0 = mh * 512;
  for (int i = wid; i < 16; i += 4) {
    int beta = i * 1024 + lane * 16;
    int row = beta >> 8, cb = (beta & 255) ^ ((row & 15) << 4);
    gload16(kb + (size_t)(m0 + row) * (C_ * 2) + cb, lK[0] + beta);
  }
  int nloc2 = (wid * 16 + (lane & 15)) * 2; // lE byte col
  for (int mc = 0; mc < 8; mc++) {
    int cur = mc & 1;
    __syncthreads(); // lK[cur] staged; prior lE store-reads done
    if (mc < 7) {
      int mnext = m0 + (mc + 1) * 64;
      for (int i = wid; i < 16; i += 4) {
        int beta = i * 1024 + lane * 16;
        int row = beta >> 8, cb = (beta & 255) ^ ((row & 15) << 4);
        gload16(kb + (size_t)(mnext + row) * (C_ * 2) + cb, lK[cur ^ 1] + beta);
      }
    }
    for (int fj = 0; fj < 4; fj++) {
      f32x4 s = z4;
      for (int ks = 0; ks < 4; ks++) {
        int row = fj * 16 + (lane & 15);
        bf16x8 ak = *(const bf16x8*)(lK[cur] + row * 256 +
                                     ((ks * 64 + (lane >> 4) * 16) ^ ((row & 15) << 4)));
        s = mfma16(ak, bq[ks], s); // A=k(m), B=q(n) -> D[m][n]
      }
      for (int r = 0; r < 4; r++) {
        float e = __expf(s[r] * kScale);
        dpart += e;
        int m = fj * 16 + (lane >> 4) * 4 + r;
        *(u16*)(lE + m * 128 + (nloc2 ^ ((m & 7) << 4))) = f2b(e);
      }
    }
    __syncthreads(); // lE complete
    for (int i = t; i < 512; i += 256) {
      int row = i >> 3, c16 = (i & 7) * 16;
      bf16x8 val = *(const bf16x8*)(lE + row * 128 + (c16 ^ ((row & 7) << 4)));
      *(bf16x8*)(etb + (size_t)(m0 + mc * 64 + row) * (N_ * 2) + nb * 2 + c16) = val;
    }
  }
  // den[n] partial for this m-half: combine the 4 lane-groups
  dpart += __shfl_xor(dpart, 16, 64);
  dpart += __shfl_xor(dpart, 32, 64);
  if (lane < 16)
    atomicAdd(&den[(size_t)bh * N_ + nb + wid * 16 + lane], dpart);
}

// ---------------- vscale: v[b][c][n] *= 1/den[b*4 + c/128][n] (in place) ----------------
__global__ __launch_bounds__(256) void k_vscale(u16* __restrict__ v,
                                                const float* __restrict__ den) {
  size_t i = ((size_t)blockIdx.x * 256 + threadIdx.x) * 8;
  int n = (int)(i & (N_ - 1));
  int bc = (int)(i >> 10);
  int b = bc >> 9, c = bc & 511, h = c >> 7;
  const float* dv = den + ((size_t)(b * 4 + h)) * N_ + n;
  float4 d0 = *(const float4*)(dv);
  float4 d1 = *(const float4*)(dv + 4);
  u16* p = v + i;
  short4v a = *(short4v*)p, bb = *(short4v*)(p + 4);
  u16 o[8];
  o[0] = f2b(b2f((u16)a[0]) / d0.x);
  o[1] = f2b(b2f((u16)a[1]) / d0.y);
  o[2] = f2b(b2f((u16)a[2]) / d0.z);
  o[3] = f2b(b2f((u16)a[3]) / d0.w);
  o[4] = f2b(b2f((u16)bb[0]) / d1.x);
  o[5] = f2b(b2f((u16)bb[1]) / d1.y);
  o[6] = f2b(b2f((u16)bb[2]) / d1.z);
  o[7] = f2b(b2f((u16)bb[3]) / d1.w);
  short4v r0 = {(short)o[0], (short)o[1], (short)o[2], (short)o[3]};
  short4v r1 = {(short)o[4], (short)o[5], (short)o[6], (short)o[7]};
  *(short4v*)p = r0;
  *(short4v*)(p + 4) = r1;
}

// ---------------- pass B: pure GEMM o = v' . E^T + gate dot ----------------
__global__ __launch_bounds__(256) void k_passB(const u16* __restrict__ v,
                                               const u16* __restrict__ et,
                                               const float* __restrict__ gw,
                                               float* __restrict__ out0,
                                               float* __restrict__ o1,
                                               float* __restrict__ g) {
  __shared__ char smem[32768];
  __shared__ float gacc[128];
  int bh = blockIdx.x, mt = blockIdx.y, nh = blockIdx.z;
  int b = bh >> 2, h = bh & 3;
  const char* Ab = (const char*)(v + ((size_t)b * C_ + h * DK_) * N_) + nh * 1024;
  const char* Bb = (const char*)(et + (size_t)bh * N_ * N_ + (size_t)mt * 128 * N_) + nh * 1024;
  float* ob = (nh ? o1 : out0) + ((size_t)b * C_ + h * DK_) * N_ + mt * 128;
  int t = threadIdx.x, lane = t & 63, wid = t >> 6;
  int wr = wid >> 1, wc = wid & 1;
  if (t < 128) gacc[t] = 0.f;
  const f32x4 z4 = {0.f, 0.f, 0.f, 0.f};
  f32x4 acc[4][4];
  for (int i = 0; i < 4; i++)
    for (int j = 0; j < 4; j++) acc[i][j] = z4;

  char* lA = smem;
  char* lB = smem + 16384;
  for (int ko = 0; ko < 512; ko += 64) {
    __syncthreads();
    for (int i = wid; i < 16; i += 4) {
      int beta = i * 1024 + lane * 16;
      int row = beta >> 7, cb = (beta & 127) ^ ((row & 7) << 4);
      gload16(Ab + (size_t)row * 2048 + ko * 2 + cb, lA + beta);
    }
    for (int i = wid; i < 16; i += 4) {
      int beta = i * 1024 + lane * 16;
      int row = beta >> 7, cb = (beta & 127) ^ ((row & 7) << 4);
      gload16(Bb + (size_t)row * 2048 + ko * 2 + cb, lB + beta);
    }
    __syncthreads();
    for (int ks = 0; ks < 2; ks++) {
      int kb = ks * 64 + (lane >> 4) * 16;
      bf16x8 af[4], bfr[4];
      for (int fi = 0; fi < 4; fi++) {
        int row = wr * 64 + fi * 16 + (lane & 15);
        af[fi] = *(const bf16x8*)(lA + row * 128 + (kb ^ ((row & 7) << 4)));
      }
      for (int fj = 0; fj < 4; fj++) {
        int row = wc * 64 + fj * 16 + (lane & 15);
        bfr[fj] = *(const bf16x8*)(lB + row * 128 + (kb ^ ((row & 7) << 4)));
      }
      for (int fi = 0; fi < 4; fi++)
        for (int fj = 0; fj < 4; fj++)
          acc[fi][fj] = mfma16(af[fi], bfr[fj], acc[fi][fj]);
    }
  }
  // epilogue: f32 stores + gate partial (D[d][m]: d rows, m cols)
  for (int fj = 0; fj < 4; fj++) {
    int mcol = wc * 64 + fj * 16 + (lane & 15);
    float part = 0.f;
    for (int fi = 0; fi < 4; fi++) {
      int d = wr * 64 + fi * 16 + (lane >> 4) * 4;
      float4 gwv = *(const float4*)(gw + h * DK_ + d);
      float ga[4] = {gwv.x, gwv.y, gwv.z, gwv.w};
      for (int r = 0; r < 4; r++) {
        float val = acc[fi][fj][r];
        ob[(size_t)(d + r) * N_ + mcol] = val;
        part += ga[r] * val;
      }
    }
    atomicAdd(&gacc[mcol], part);
  }
  __syncthreads();
  if (t < 128) atomicAdd(&g[(size_t)b * N_ + mt * 128 + t], gacc[t]);
}

// ---------------- gate apply: out = (out + o1) * (1 + sigmoid(g + gb)) ----------------
__global__ __launch_bounds__(256) void k_gate_apply(const float* __restrict__ g,
                                                    const float* __restrict__ gb,
                                                    const float* __restrict__ o1,
                                                    float* __restrict__ out) {
  size_t i = ((size_t)blockIdx.x * 256 + threadIdx.x) * 4;
  int b = (int)(i / ((size_t)C_ * N_));
  int n = (int)(i & (N_ - 1));
  float4 gv = *(const float4*)(g + (size_t)b * N_ + n);
  float bias = gb[0];
  float4 v0 = *(float4*)(out + i);
  float4 v1 = *(const float4*)(o1 + i);
  float ox = v0.x + v1.x, oy = v0.y + v1.y, oz = v0.z + v1.z, ow = v0.w + v1.w;
  ox *= 1.f + 1.f / (1.f + __expf(-(gv.x + bias)));
  oy *= 1.f + 1.f / (1.f + __expf(-(gv.y + bias)));
  oz *= 1.f + 1.f / (1.f + __expf(-(gv.z + bias)));
  ow *= 1.f + 1.f / (1.f + __expf(-(gv.w + bias)));
  float4 r = {ox, oy, oz, ow};
  *(float4*)(out + i) = r;
}

extern "C" void kernel_launch(void* const* d_in, const int* in_sizes, int n_in,
                              void* d_out, int out_size, void* d_ws, size_t ws_size,
                              hipStream_t stream) {
  const float* x    = (const float*)d_in[0];
  const float* wq   = (const float*)d_in[1];
  const float* bq   = (const float*)d_in[2];
  const float* wk   = (const float*)d_in[3];
  const float* bk   = (const float*)d_in[4];
  const float* wv   = (const float*)d_in[5];
  const float* bv   = (const float*)d_in[6];
  const float* fc1w = (const float*)d_in[7];
  const float* fc1b = (const float*)d_in[8];
  const float* fc2w = (const float*)d_in[9];
  const float* fc2b = (const float*)d_in[10];
  const float* gw   = (const float*)d_in[11];
  const float* gb   = (const float*)d_in[12];
  float* out = (float*)d_out;
  char* ws = (char*)d_ws;

  float* p   = (float*)(ws + OFF_P);
  float* ssc = (float*)(ws + OFF_SS);
  u16* wb  = (u16*)(ws + OFF_WB);
  u16* xt  = (u16*)(ws + OFF_XT);
  u16* qt  = (u16*)(ws + OFF_QT);
  u16* kt  = (u16*)(ws + OFF_KT);
  u16* v   = (u16*)(ws + OFF_V);
  float* den = (float*)(ws + OFF_DEN);
  float* g   = (float*)(ws + OFF_G);
  float* o1  = (float*)(ws + OFF_O1);
  u16* et  = (u16*)(ws + OFF_E);

  k_pool<<<B_ * C_, 64, 0, stream>>>(x, p);
  k_castw_zero<<<928, 256, 0, stream>>>(wq, wk, wv, wb, g, den);
  k_se<<<B_, 256, 0, stream>>>(p, fc1w, fc1b, fc2w, fc2b, ssc);
  k_xt<<<dim3(16, 8, B_), 256, 0, stream>>>(x, ssc, xt);
  k_qkv<<<dim3(32, B_ * 3), 256, 0, stream>>>(xt, wb, bq, bk, bv, qt, kt, v);
  k_passA<<<dim3(32, 16, 2), 256, 0, stream>>>(qt, kt, et, den);
  k_vscale<<<2048, 256, 0, stream>>>(v, den);
  k_passB<<<dim3(32, 8, 2), 256, 0, stream>>>(v, et, gw, out, o1, g);
  k_gate_apply<<<B_ * C_ * N_ / 1024, 256, 0, stream>>>(g, gb, o1, out);
}

// Round 15
// 117.840 us; speedup vs baseline: 1.2062x; 1.0141x over previous
//
#include <hip/hip_runtime.h>
#include <hip/hip_bf16.h>

#define B_ 8
#define C_ 512
#define N_ 1024
#define HEADS_ 4
#define DK_ 128
#define R_ 128

typedef float f32x4 __attribute__((ext_vector_type(4)));
typedef __bf16 bf16x8 __attribute__((ext_vector_type(8)));
typedef short short4v __attribute__((ext_vector_type(4)));
typedef short short8v __attribute__((ext_vector_type(8)));
typedef unsigned short u16;

constexpr float kScale = 0.08838834764831845f; // 1/sqrt(128)

// ---- workspace layout (bytes); ws_size = 256 MiB ----
#define OFF_P   0u
#define OFF_SS  16384u
#define OFF_WB  32768u
#define OFF_XT  1605632u
#define OFF_QT  9994240u
#define OFF_KT  18382848u
#define OFF_V   26771456u
#define OFF_DEN 35160064u                // den [B*H][N] f32 (atomic) 128KB
#define OFF_G   35291136u                // gate dot [B][N] f32    32KB
#define OFF_O1  35323904u                // o half-1 [B][C][N] f32 16MB
#define OFF_E   52101120u                // E^T [B*H][m=N][n=N] bf16 64MB

__device__ __forceinline__ u16 f2b(float f) {
  __hip_bfloat16 h = __float2bfloat16(f);
  return __builtin_bit_cast(u16, h);
}
__device__ __forceinline__ float b2f(u16 u) {
  return __builtin_bit_cast(float, (unsigned)u << 16);
}

typedef const __attribute__((address_space(1))) unsigned int* gptr_t;
typedef __attribute__((address_space(3))) unsigned int* lptr_t;
__device__ __forceinline__ void gload16(const void* g, void* l) {
  __builtin_amdgcn_global_load_lds((gptr_t)g, (lptr_t)l, 16, 0, 0);
}

__device__ __forceinline__ f32x4 mfma16(bf16x8 a, bf16x8 b, f32x4 c) {
  return __builtin_amdgcn_mfma_f32_16x16x32_bf16(a, b, c, 0, 0, 0);
}

// ---------------- front: pool + castw + zero g + zero den ----------------
__global__ __launch_bounds__(256) void k_front(const float* __restrict__ x,
                                               const float* __restrict__ wq,
                                               const float* __restrict__ wk,
                                               const float* __restrict__ wv,
                                               u16* __restrict__ wb,
                                               float* __restrict__ g,
                                               float* __restrict__ den,
                                               float* __restrict__ p) {
  int bid = blockIdx.x, t = threadIdx.x;
  if (bid < 1024) { // pool: 4 waves/block, one bc row each
    int lane = t & 63, w = t >> 6;
    int bc = bid * 4 + w;
    const float4* row = (const float4*)(x + (size_t)bc * N_);
    float s = 0.f;
    for (int j = 0; j < 4; j++) {
      float4 v = row[lane + 64 * j];
      s += v.x + v.y + v.z + v.w;
    }
    for (int o = 32; o > 0; o >>= 1) s += __shfl_down(s, o, 64);
    if (lane == 0) p[bc] = s * (1.0f / N_);
    return;
  }
  if (bid < 1792) { // castw
    int i = (bid - 1024) * 256 + t;
    int idx = i * 4;
    const float* srcs[3] = {wq, wk, wv};
    int w = idx / (C_ * C_), off = idx % (C_ * C_);
    float4 v = *(const float4*)(srcs[w] + off);
    u16* d = wb + idx;
    d[0] = f2b(v.x); d[1] = f2b(v.y); d[2] = f2b(v.z); d[3] = f2b(v.w);
    return;
  }
  if (bid < 1824) { // zero g
    g[(bid - 1792) * 256 + t] = 0.f;
    return;
  }
  den[(bid - 1824) * 256 + t] = 0.f; // zero den
}

// ---------------- SE MLP ----------------
__global__ __launch_bounds__(256) void k_se(const float* __restrict__ p,
                                            const float* __restrict__ fc1w,
                                            const float* __restrict__ fc1b,
                                            const float* __restrict__ fc2w,
                                            const float* __restrict__ fc2b,
                                            float* __restrict__ ss) {
  __shared__ float pl[C_];
  __shared__ float f1[R_];
  int b = blockIdx.x, t = threadIdx.x;
  for (int c = t; c < C_; c += 256) pl[c] = p[b * C_ + c];
  __syncthreads();
  if (t < R_) {
    float a = fc1b[t];
    for (int c = 0; c < C_; c++) a += pl[c] * fc1w[t * C_ + c];
    f1[t] = fmaxf(a, 0.f);
  }
  __syncthreads();
  for (int c = t; c < C_; c += 256) {
    float a = fc2b[c];
    for (int j = 0; j < R_; j++) a += f1[j] * fc2w[c * R_ + j];
    ss[b * C_ + c] = 1.f + 1.f / (1.f + __expf(-a));
  }
}

// ---------------- x1^T (vectorized 16B stores) ----------------
__global__ __launch_bounds__(256) void k_xt(const float* __restrict__ x,
                                            const float* __restrict__ ss,
                                            u16* __restrict__ xt) {
  int b = blockIdx.z, c0 = blockIdx.y * 64, n0 = blockIdx.x * 64;
  __shared__ float tile[64][65];
  int t = threadIdx.x;
  int cr = t >> 4, nc4 = (t & 15) * 4;
  for (int j = 0; j < 4; j++) {
    int c = cr + j * 16;
    float sc = ss[b * C_ + c0 + c];
    float4 v = *(const float4*)(x + ((size_t)b * C_ + c0 + c) * N_ + n0 + nc4);
    tile[c][nc4 + 0] = v.x * sc;
    tile[c][nc4 + 1] = v.y * sc;
    tile[c][nc4 + 2] = v.z * sc;
    tile[c][nc4 + 3] = v.w * sc;
  }
  __syncthreads();
  int nr = t >> 2, cc = (t & 3) * 16;
  short8v s0, s1;
  for (int m = 0; m < 8; m++) {
    s0[m] = (short)f2b(tile[cc + m][nr]);
    s1[m] = (short)f2b(tile[cc + 8 + m][nr]);
  }
  u16* dst = xt + ((size_t)b * N_ + n0 + nr) * C_ + c0 + cc;
  *(short8v*)dst = s0;
  *(short8v*)(dst + 8) = s1;
}

// ---------------- QKV GEMM ----------------
__global__ __launch_bounds__(256) void k_qkv(const u16* __restrict__ xt,
                                             const u16* __restrict__ wb,
                                             const float* __restrict__ bq,
                                             const float* __restrict__ bk,
                                             const float* __restrict__ bv,
                                             u16* __restrict__ qt,
                                             u16* __restrict__ kt,
                                             u16* __restrict__ v) {
  __shared__ char smem[32768];
  int b = blockIdx.y / 3, sel = blockIdx.y % 3;
  int tile = blockIdx.x;
  const char *Ab, *Bb;
  u16* out;
  const float* bias;
  int mt, nt, rstride;
  size_t xtoff = (size_t)b * N_ * C_;
  if (sel < 2) {
    mt = tile & 7; nt = tile >> 3;
    Ab = (const char*)(xt + xtoff + (size_t)mt * 128 * C_);
    Bb = (const char*)(wb + (size_t)sel * C_ * C_ + (size_t)nt * 128 * C_);
    out = (sel ? kt : qt) + xtoff;
    bias = sel ? bk : bq;
    rstride = C_ * 2;
  } else {
    mt = tile & 3; nt = tile >> 2;
    Ab = (const char*)(wb + (size_t)2 * C_ * C_ + (size_t)mt * 128 * C_);
    Bb = (const char*)(xt + xtoff + (size_t)nt * 128 * C_);
    out = v + (size_t)b * C_ * N_;
    bias = bv;
    rstride = N_ * 2;
  }
  int t = threadIdx.x, lane = t & 63, wid = t >> 6;
  int wr = wid >> 1, wc = wid & 1;
  const f32x4 z4 = {0.f, 0.f, 0.f, 0.f};
  f32x4 acc[4][4];
  for (int i = 0; i < 4; i++)
    for (int j = 0; j < 4; j++) acc[i][j] = z4;

  char* lA = smem;
  char* lB = smem + 16384;
  for (int ko = 0; ko < C_; ko += 64) {
    __syncthreads();
    for (int i = wid; i < 16; i += 4) {
      int beta = i * 1024 + lane * 16;
      int row = beta >> 7, cb = (beta & 127) ^ ((row & 7) << 4);
      gload16(Ab + (size_t)row * 1024 + ko * 2 + cb, lA + beta);
    }
    for (int i = wid; i < 16; i += 4) {
      int beta = i * 1024 + lane * 16;
      int row = beta >> 7, cb = (beta & 127) ^ ((row & 7) << 4);
      gload16(Bb + (size_t)row * 1024 + ko * 2 + cb, lB + beta);
    }
    __syncthreads();
    for (int ks = 0; ks < 2; ks++) {
      int kb = ks * 64 + (lane >> 4) * 16;
      bf16x8 af[4], bfr[4];
      for (int fi = 0; fi < 4; fi++) {
        int row = wr * 64 + fi * 16 + (lane & 15);
        af[fi] = *(const bf16x8*)(lA + row * 128 + (kb ^ ((row & 7) << 4)));
      }
      for (int fj = 0; fj < 4; fj++) {
        int row = wc * 64 + fj * 16 + (lane & 15);
        bfr[fj] = *(const bf16x8*)(lB + row * 128 + (kb ^ ((row & 7) << 4)));
      }
      for (int fi = 0; fi < 4; fi++)
        for (int fj = 0; fj < 4; fj++)
          acc[fi][fj] = mfma16(af[fi], bfr[fj], acc[fi][fj]);
    }
  }
  __syncthreads();
  for (int fi = 0; fi < 4; fi++)
    for (int fj = 0; fj < 4; fj++) {
      int colb = wc * 64 + fj * 16 + (lane & 15);
      for (int r = 0; r < 4; r++) {
        int rowb = wr * 64 + fi * 16 + (lane >> 4) * 4 + r;
        float bva = (sel < 2) ? bias[nt * 128 + colb] : bias[mt * 128 + rowb];
        float val = acc[fi][fj][r] + bva;
        int byte = rowb * 256 + ((colb * 2) ^ ((rowb & 7) << 4));
        *(u16*)(smem + byte) = f2b(val);
      }
    }
  __syncthreads();
  for (int i = t; i < 2048; i += 256) {
    int row = i >> 4, cb = (i & 15) * 16;
    bf16x8 val = *(const bf16x8*)(smem + row * 256 + (cb ^ ((row & 7) << 4)));
    *(bf16x8*)((char*)out + (size_t)(mt * 128 + row) * rstride + nt * 256 + cb) = val;
  }
}

// ---------------- pass A: E^T[m][n] = exp(scale*S[n,m]) + den (atomic) ----------------
// D[n][m] orientation (A=q(n rows), B=k(m rows)): lane's r=0..3 values are 4
// consecutive n at fixed m -> ONE ds_write_b64 per fj (was 16 b16 writes/chunk).
// grid (bh, 16 nb of 64, 2 m-halves); 64-m chunks, LDS 40KB -> 4 blocks/CU.
__global__ __launch_bounds__(256) void k_passA(const u16* __restrict__ qt,
                                               const u16* __restrict__ kt,
                                               u16* __restrict__ et,
                                               float* __restrict__ den) {
  __shared__ char lK[2][16384]; // [64 m][256B rows, 4-bit swz], x2
  __shared__ char lE[8192];     // [64 m][64 n] u16, 128B rows, 3-bit swz
  int bh = blockIdx.x, nb = blockIdx.y * 64, mh = blockIdx.z;
  int b = bh >> 2, h = bh & 3;
  const char* qb = (const char*)(qt + (size_t)b * N_ * C_ + h * DK_);
  const char* kb = (const char*)(kt + (size_t)b * N_ * C_ + h * DK_);
  char* etb = (char*)(et + (size_t)bh * N_ * N_);
  int t = threadIdx.x, lane = t & 63, wid = t >> 6; // wid 0..3
  // A operand: wave's 16 q-rows (n), fixed across chunks
  bf16x8 aq[4];
  {
    const char* qr = qb + (size_t)(nb + wid * 16 + (lane & 15)) * (C_ * 2);
    for (int ks = 0; ks < 4; ks++)
      aq[ks] = *(const bf16x8*)(qr + ks * 64 + (lane >> 4) * 16);
  }
  float dpart[4] = {0.f, 0.f, 0.f, 0.f};
  const f32x4 z4 = {0.f, 0.f, 0.f, 0.f};
  int m0 = mh * 512;
  for (int i = wid; i < 16; i += 4) {
    int beta = i * 1024 + lane * 16;
    int row = beta >> 8, cb = (beta & 255) ^ ((row & 15) << 4);
    gload16(kb + (size_t)(m0 + row) * (C_ * 2) + cb, lK[0] + beta);
  }
  int nloc2 = (wid * 16 + (lane >> 4) * 4) * 2; // lE byte col base (8B aligned)
  for (int mc = 0; mc < 8; mc++) {
    int cur = mc & 1;
    __syncthreads(); // lK[cur] staged; prior lE copy-reads done
    if (mc < 7) {
      int mnext = m0 + (mc + 1) * 64;
      for (int i = wid; i < 16; i += 4) {
        int beta = i * 1024 + lane * 16;
        int row = beta >> 8, cb = (beta & 255) ^ ((row & 15) << 4);
        gload16(kb + (size_t)(mnext + row) * (C_ * 2) + cb, lK[cur ^ 1] + beta);
      }
    }
    for (int fj = 0; fj < 4; fj++) {
      f32x4 s = z4;
      for (int ks = 0; ks < 4; ks++) {
        int row = fj * 16 + (lane & 15);
        bf16x8 bk_ = *(const bf16x8*)(lK[cur] + row * 256 +
                                      ((ks * 64 + (lane >> 4) * 16) ^ ((row & 15) << 4)));
        s = mfma16(aq[ks], bk_, s); // A=q(n), B=k(m) -> D[n][m]
      }
      int mloc = fj * 16 + (lane & 15);
      short4v ev;
      for (int r = 0; r < 4; r++) {
        float e = __expf(s[r] * kScale);
        dpart[r] += e;
        ev[r] = (short)f2b(e);
      }
      *(short4v*)(lE + mloc * 128 + (nloc2 ^ ((mloc & 7) << 4))) = ev;
    }
    __syncthreads(); // lE complete
    for (int i = t; i < 512; i += 256) {
      int row = i >> 3, c16 = (i & 7) * 16;
      bf16x8 val = *(const bf16x8*)(lE + row * 128 + (c16 ^ ((row & 7) << 4)));
      *(bf16x8*)(etb + (size_t)(m0 + mc * 64 + row) * (N_ * 2) + nb * 2 + c16) = val;
    }
  }
  // den[n] partial: sum over the 16 m-lanes (lane&15 group) for each r
  for (int r = 0; r < 4; r++) {
    float vv = dpart[r];
    vv += __shfl_xor(vv, 1, 64);
    vv += __shfl_xor(vv, 2, 64);
    vv += __shfl_xor(vv, 4, 64);
    vv += __shfl_xor(vv, 8, 64);
    dpart[r] = vv;
  }
  if ((lane & 15) == 0) {
    int n = nb + wid * 16 + (lane >> 4) * 4;
    for (int r = 0; r < 4; r++)
      atomicAdd(&den[(size_t)bh * N_ + n + r], dpart[r]);
  }
}

// ---------------- vscale: v[b][c][n] *= 1/den[b*4 + c/128][n] (in place) ----------------
__global__ __launch_bounds__(256) void k_vscale(u16* __restrict__ v,
                                                const float* __restrict__ den) {
  size_t i = ((size_t)blockIdx.x * 256 + threadIdx.x) * 8;
  int n = (int)(i & (N_ - 1));
  int bc = (int)(i >> 10);
  int b = bc >> 9, c = bc & 511, h = c >> 7;
  const float* dv = den + ((size_t)(b * 4 + h)) * N_ + n;
  float4 d0 = *(const float4*)(dv);
  float4 d1 = *(const float4*)(dv + 4);
  u16* p = v + i;
  short4v a = *(short4v*)p, bb = *(short4v*)(p + 4);
  u16 o[8];
  o[0] = f2b(b2f((u16)a[0]) / d0.x);
  o[1] = f2b(b2f((u16)a[1]) / d0.y);
  o[2] = f2b(b2f((u16)a[2]) / d0.z);
  o[3] = f2b(b2f((u16)a[3]) / d0.w);
  o[4] = f2b(b2f((u16)bb[0]) / d1.x);
  o[5] = f2b(b2f((u16)bb[1]) / d1.y);
  o[6] = f2b(b2f((u16)bb[2]) / d1.z);
  o[7] = f2b(b2f((u16)bb[3]) / d1.w);
  short4v r0 = {(short)o[0], (short)o[1], (short)o[2], (short)o[3]};
  short4v r1 = {(short)o[4], (short)o[5], (short)o[6], (short)o[7]};
  *(short4v*)p = r0;
  *(short4v*)(p + 4) = r1;
}

// ---------------- pass B: pure GEMM o = v' . E^T + gate dot ----------------
__global__ __launch_bounds__(256) void k_passB(const u16* __restrict__ v,
                                               const u16* __restrict__ et,
                                               const float* __restrict__ gw,
                                               float* __restrict__ out0,
                                               float* __restrict__ o1,
                                               float* __restrict__ g) {
  __shared__ char smem[32768];
  __shared__ float gacc[128];
  int bh = blockIdx.x, mt = blockIdx.y, nh = blockIdx.z;
  int b = bh >> 2, h = bh & 3;
  const char* Ab = (const char*)(v + ((size_t)b * C_ + h * DK_) * N_) + nh * 1024;
  const char* Bb = (const char*)(et + (size_t)bh * N_ * N_ + (size_t)mt * 128 * N_) + nh * 1024;
  float* ob = (nh ? o1 : out0) + ((size_t)b * C_ + h * DK_) * N_ + mt * 128;
  int t = threadIdx.x, lane = t & 63, wid = t >> 6;
  int wr = wid >> 1, wc = wid & 1;
  if (t < 128) gacc[t] = 0.f;
  const f32x4 z4 = {0.f, 0.f, 0.f, 0.f};
  f32x4 acc[4][4];
  for (int i = 0; i < 4; i++)
    for (int j = 0; j < 4; j++) acc[i][j] = z4;

  char* lA = smem;
  char* lB = smem + 16384;
  for (int ko = 0; ko < 512; ko += 64) {
    __syncthreads();
    for (int i = wid; i < 16; i += 4) {
      int beta = i * 1024 + lane * 16;
      int row = beta >> 7, cb = (beta & 127) ^ ((row & 7) << 4);
      gload16(Ab + (size_t)row * 2048 + ko * 2 + cb, lA + beta);
    }
    for (int i = wid; i < 16; i += 4) {
      int beta = i * 1024 + lane * 16;
      int row = beta >> 7, cb = (beta & 127) ^ ((row & 7) << 4);
      gload16(Bb + (size_t)row * 2048 + ko * 2 + cb, lB + beta);
    }
    __syncthreads();
    for (int ks = 0; ks < 2; ks++) {
      int kb = ks * 64 + (lane >> 4) * 16;
      bf16x8 af[4], bfr[4];
      for (int fi = 0; fi < 4; fi++) {
        int row = wr * 64 + fi * 16 + (lane & 15);
        af[fi] = *(const bf16x8*)(lA + row * 128 + (kb ^ ((row & 7) << 4)));
      }
      for (int fj = 0; fj < 4; fj++) {
        int row = wc * 64 + fj * 16 + (lane & 15);
        bfr[fj] = *(const bf16x8*)(lB + row * 128 + (kb ^ ((row & 7) << 4)));
      }
      for (int fi = 0; fi < 4; fi++)
        for (int fj = 0; fj < 4; fj++)
          acc[fi][fj] = mfma16(af[fi], bfr[fj], acc[fi][fj]);
    }
  }
  // epilogue: f32 stores + gate partial (D[d][m]: d rows, m cols)
  for (int fj = 0; fj < 4; fj++) {
    int mcol = wc * 64 + fj * 16 + (lane & 15);
    float part = 0.f;
    for (int fi = 0; fi < 4; fi++) {
      int d = wr * 64 + fi * 16 + (lane >> 4) * 4;
      float4 gwv = *(const float4*)(gw + h * DK_ + d);
      float ga[4] = {gwv.x, gwv.y, gwv.z, gwv.w};
      for (int r = 0; r < 4; r++) {
        float val = acc[fi][fj][r];
        ob[(size_t)(d + r) * N_ + mcol] = val;
        part += ga[r] * val;
      }
    }
    atomicAdd(&gacc[mcol], part);
  }
  __syncthreads();
  if (t < 128) atomicAdd(&g[(size_t)b * N_ + mt * 128 + t], gacc[t]);
}

// ---------------- gate apply: out = (out + o1) * (1 + sigmoid(g + gb)) ----------------
__global__ __launch_bounds__(256) void k_gate_apply(const float* __restrict__ g,
                                                    const float* __restrict__ gb,
                                                    const float* __restrict__ o1,
                                                    float* __restrict__ out) {
  size_t i = ((size_t)blockIdx.x * 256 + threadIdx.x) * 4;
  int b = (int)(i / ((size_t)C_ * N_));
  int n = (int)(i & (N_ - 1));
  float4 gv = *(const float4*)(g + (size_t)b * N_ + n);
  float bias = gb[0];
  float4 v0 = *(float4*)(out + i);
  float4 v1 = *(const float4*)(o1 + i);
  float ox = v0.x + v1.x, oy = v0.y + v1.y, oz = v0.z + v1.z, ow = v0.w + v1.w;
  ox *= 1.f + 1.f / (1.f + __expf(-(gv.x + bias)));
  oy *= 1.f + 1.f / (1.f + __expf(-(gv.y + bias)));
  oz *= 1.f + 1.f / (1.f + __expf(-(gv.z + bias)));
  ow *= 1.f + 1.f / (1.f + __expf(-(gv.w + bias)));
  float4 r = {ox, oy, oz, ow};
  *(float4*)(out + i) = r;
}

extern "C" void kernel_launch(void* const* d_in, const int* in_sizes, int n_in,
                              void* d_out, int out_size, void* d_ws, size_t ws_size,
                              hipStream_t stream) {
  const float* x    = (const float*)d_in[0];
  const float* wq   = (const float*)d_in[1];
  const float* bq   = (const float*)d_in[2];
  const float* wk   = (const float*)d_in[3];
  const float* bk   = (const float*)d_in[4];
  const float* wv   = (const float*)d_in[5];
  const float* bv   = (const float*)d_in[6];
  const float* fc1w = (const float*)d_in[7];
  const float* fc1b = (const float*)d_in[8];
  const float* fc2w = (const float*)d_in[9];
  const float* fc2b = (const float*)d_in[10];
  const float* gw   = (const float*)d_in[11];
  const float* gb   = (const float*)d_in[12];
  float* out = (float*)d_out;
  char* ws = (char*)d_ws;

  float* p   = (float*)(ws + OFF_P);
  float* ssc = (float*)(ws + OFF_SS);
  u16* wb  = (u16*)(ws + OFF_WB);
  u16* xt  = (u16*)(ws + OFF_XT);
  u16* qt  = (u16*)(ws + OFF_QT);
  u16* kt  = (u16*)(ws + OFF_KT);
  u16* v   = (u16*)(ws + OFF_V);
  float* den = (float*)(ws + OFF_DEN);
  float* g   = (float*)(ws + OFF_G);
  float* o1  = (float*)(ws + OFF_O1);
  u16* et  = (u16*)(ws + OFF_E);

  k_front<<<1952, 256, 0, stream>>>(x, wq, wk, wv, wb, g, den, p);
  k_se<<<B_, 256, 0, stream>>>(p, fc1w, fc1b, fc2w, fc2b, ssc);
  k_xt<<<dim3(16, 8, B_), 256, 0, stream>>>(x, ssc, xt);
  k_qkv<<<dim3(32, B_ * 3), 256, 0, stream>>>(xt, wb, bq, bk, bv, qt, kt, v);
  k_passA<<<dim3(32, 16, 2), 256, 0, stream>>>(qt, kt, et, den);
  k_vscale<<<2048, 256, 0, stream>>>(v, den);
  k_passB<<<dim3(32, 8, 2), 256, 0, stream>>>(v, et, gw, out, o1, g);
  k_gate_apply<<<B_ * C_ * N_ / 1024, 256, 0, stream>>>(g, gb, o1, out);
}